// Round 10
// baseline (4192.246 us; speedup 1.0000x reference)
//
#include <hip/hip_runtime.h>
#include <math.h>

// ---------------------------------------------------------------------------
// LSTM encoder-decoder, 3-term bf16 MFMA (hi/lo split), persistent kernel.
// 8 XCD-local groups (bid&7), 32 blocks x 512 thr each, own 32 batch rows.
// Gate-grouped columns (r9-proven): z stays in-block; only softmax (max,sum)
// partials cross blocks. NEW SYNC: per-block progress WORDS (128B apart).
// Arrive = ONE relaxed atomic store to own word (no same-address RMW
// serialization — r9's 3.3us/sync was 32 RMWs on one L2 word serializing at
// ~250cyc each). Wait = wave-parallel gather (lanes 0..31 load all words in
// one pipelined L2 round trip) + 6-shfl min reduce + buffer_inv sc0.
// ---------------------------------------------------------------------------

typedef __attribute__((ext_vector_type(8))) short bf16x8;
typedef __attribute__((ext_vector_type(8))) unsigned short u16x8;
typedef __attribute__((ext_vector_type(4))) float f32x4;

// ws layout (float offsets)
#define OFS_XW     0u          // 256*2048 f32 (gate-grouped, block-self-consumed)
#define OFS_HEH    524288u     // enc h hi: 256*512 bf16 (=65536 f)
#define OFS_HEL    589824u
#define OFS_HD     655360u     // dec h: [par2][dir2][hi/lo][256*256 bf16=32768f]
#define OFS_HSEQ   917504u     // 256*64*512 bf16 (=4194304 f)
#define OFS_BENCH  5111808u    // 72*2048*8 bf16 packed (gate-grouped cols)
#define OFS_BENCL  5701632u
#define OFS_BDKH   6291456u    // 64*2048*8
#define OFS_BDKL   6815744u
#define OFS_BDUH   7340032u    // 32*2048*8
#define OFS_BDUL   7602176u
#define OFS_PST    7864320u    // pst1: 8g*32row*32w*2f =16384; pst2: +16384
#define OFS_BAR    7897088u    // 40960 u32: per g 5120: A+0 B+1024 C+2048
                               //   D0+3072 D1+3584 E+4096 (slots stride 32)
#define WS_FLOATS  7938048u    // ~31.8 MB

__device__ __forceinline__ unsigned short bf_hi(float f) {
    union { float f; unsigned u; } v; v.f = f;
    unsigned r = v.u + 0x7fffu + ((v.u >> 16) & 1u);
    return (unsigned short)(r >> 16);
}
__device__ __forceinline__ float bf2f(unsigned short h) {
    union { unsigned u; float f; } v; v.u = ((unsigned)h) << 16;
    return v.f;
}
__device__ __forceinline__ void split2(float f, unsigned short& hi, unsigned short& lo) {
    hi = bf_hi(f);
    lo = bf_hi(f - bf2f(hi));
}
__device__ __forceinline__ float sigm(float x) { return 1.0f / (1.0f + __expf(-x)); }

// ---- arrive+wait: per-block progress words, wave-parallel poll ------------
// arr[slot*32] words. Store own word = val (plain relaxed atomic store, L2,
// no RMW). Wave 0 gathers all nslots words (parallel loads, distinct 128B
// lines), 6-shfl min-reduce, repeat until min >= tgt. L1-only inv at exit.
__device__ __forceinline__ void arrive_wait(unsigned* arr, int slot,
                                            unsigned val, unsigned tgt,
                                            int nslots) {
    asm volatile("s_waitcnt vmcnt(0) lgkmcnt(0)" ::: "memory");  // publish
    __syncthreads();
    if (threadIdx.x < 64) {
        if (threadIdx.x == 0)
            __hip_atomic_store(arr + slot * 32, val, __ATOMIC_RELAXED,
                               __HIP_MEMORY_SCOPE_AGENT);
        const int l = threadIdx.x;
        const int idx = (l < nslots) ? l : 0;
        const long long t0 = clock64();
        for (;;) {
            unsigned v = __hip_atomic_load(arr + idx * 32, __ATOMIC_RELAXED,
                                           __HIP_MEMORY_SCOPE_AGENT);
            #pragma unroll
            for (int m = 32; m; m >>= 1) {
                const unsigned o = (unsigned)__shfl_xor((int)v, m, 64);
                v = (o < v) ? o : v;
            }
            if (v >= tgt) break;
            __builtin_amdgcn_s_sleep(1);
            if (clock64() - t0 > 4000000LL) break;   // deadlock guard only
        }
        asm volatile("buffer_inv sc0" ::: "memory"); // L1 invalidate only
    }
    __syncthreads();
}

// 16-lane-span reductions (xor masks 1..8 stay inside a 16-lane row span)
__device__ __forceinline__ float red16max(float v) {
    #pragma unroll
    for (int m = 8; m; m >>= 1) v = fmaxf(v, __shfl_xor(v, m, 64));
    return v;
}
__device__ __forceinline__ float red16sum(float v) {
    #pragma unroll
    for (int m = 8; m; m >>= 1) v += __shfl_xor(v, m, 64);
    return v;
}

// ---------------------------------------------------------------------------
// weight pack: fp32 -> bf16 hi/lo, frag layout [kg][2048 packed cols][8]
// GATE-GROUPED packed col n: w=n>>6, gate=(n>>4)&3, ul=n&15.
// MODE 0 also zero-initializes the 40960 barrier words (replay-safe).
// ---------------------------------------------------------------------------
template <int MODE>
__global__ __launch_bounds__(256) void pack_b(
    const float* __restrict__ S0, const float* __restrict__ S1,
    unsigned short* __restrict__ H, unsigned short* __restrict__ L,
    unsigned* __restrict__ bar)
{
    const int idx = blockIdx.x * 256 + threadIdx.x;
    if (MODE == 0 && idx < 40960) bar[idx] = 0u;
    const int n = idx & 2047, kg = idx >> 11;
    int sc;
    const float* Sd;
    if (MODE == 0) {
        sc = ((n >> 4) & 3) * 512 + (n >> 6) * 16 + (n & 15);
        Sd = nullptr;
    } else {
        const int dir = n >> 10, bw = (n >> 6) & 15;
        sc = ((n >> 4) & 3) * 256 + bw * 16 + (n & 15);
        Sd = dir ? S1 : S0;
    }
    u16x8 h8, l8;
    #pragma unroll
    for (int j = 0; j < 8; ++j) {
        const int k = kg * 8 + j;
        float v;
        if (MODE == 0) v = (k < 64) ? S0[(size_t)k * 2048 + sc] : S1[(size_t)(k - 64) * 2048 + sc];
        else           v = Sd[(size_t)k * 1024 + sc];
        unsigned short hh, ll; split2(v, hh, ll);
        h8[j] = hh; l8[j] = ll;
    }
    *(u16x8*)(H + (size_t)idx * 8) = h8;
    *(u16x8*)(L + (size_t)idx * 8) = l8;
}

// ===========================================================================
// Persistent kernel. 256 blocks x 512 thr (8 waves), LDS ~74KB.
// g=bid&7 (XCD), w=bid>>3 (0..31).
// ===========================================================================
__global__ __launch_bounds__(512, 2) void lstm_all(
    const float* __restrict__ x, const float* __restrict__ encB,
    const float* __restrict__ dfB, const float* __restrict__ dbB,
    const float* __restrict__ dK, const float* __restrict__ dnB,
    float* __restrict__ out, float* __restrict__ ws)
{
    const int bid = blockIdx.x, tid = threadIdx.x;
    const int g = bid & 7, w = bid >> 3;          // group (XCD), slot 0..31
    const int lane = tid & 63, wid = tid >> 6;
    const int mh = wid & 1, nh = wid >> 1;        // 2 x 4 wave grid; nh = gate
    const int l16 = lane >> 4, lr = lane & 15;
    const int lrow = mh * 16 + lr;                // local A row
    const int grow = g * 32 + lrow;               // global batch row
    const int ncl  = nh * 16 + lr;                // block-local col 0..63
    const int gcolp = w * 64 + ncl;               // packed global col
    const int urow = tid >> 4, ul = tid & 15;     // update ids: row, unit

    float* xw = ws + OFS_XW;
    unsigned short* hEHu = (unsigned short*)(ws + OFS_HEH);
    unsigned short* hELu = (unsigned short*)(ws + OFS_HEL);
    unsigned short* hseqb = (unsigned short*)(ws + OFS_HSEQ);
    const unsigned short* BeH = (const unsigned short*)(ws + OFS_BENCH);
    const unsigned short* BeL = (const unsigned short*)(ws + OFS_BENCL);
    const unsigned short* BkH = (const unsigned short*)(ws + OFS_BDKH);
    const unsigned short* BkL = (const unsigned short*)(ws + OFS_BDKL);
    const unsigned short* BuH = (const unsigned short*)(ws + OFS_BDUH);
    const unsigned short* BuL = (const unsigned short*)(ws + OFS_BDUL);
    float* pst1 = ws + OFS_PST + (unsigned)g * 2048u;
    float* pst2 = ws + OFS_PST + 16384u + (unsigned)g * 2048u;
    unsigned* barg = (unsigned*)(ws + OFS_BAR) + g * 5120;
    unsigned* pA = barg + 0;
    unsigned* pB = barg + 1024;
    unsigned* pC = barg + 2048;
    unsigned* pE = barg + 4096;

    // LDS: B_hi slice (enc kg 8..71: 64kg x 64col x 8 = 64KB) + zt [64][33]
    __shared__ __align__(16) unsigned short sBe[32768];
    __shared__ __align__(16) float zt[2112];

    // dec h pointers [par][hi/lo] for this block's dir
    const int dir = w >> 4, bw = w & 15;
    unsigned* pD = barg + 3072 + dir * 512;
    unsigned short* hd[2][2];
    #pragma unroll
    for (int p = 0; p < 2; ++p)
        #pragma unroll
        for (int hl_ = 0; hl_ < 2; ++hl_)
            hd[p][hl_] = (unsigned short*)(ws + OFS_HD +
                          (unsigned)((p * 2 + dir) * 2 + hl_) * 32768u);

    // ---- init: zero own h slices (enc + dec both parities) ----
    {
        const size_t he = (size_t)(g * 32 + urow) * 512 + w * 16 + ul;
        hEHu[he] = 0; hELu[he] = 0;
        const size_t hdix = (size_t)(g * 32 + urow) * 256 + bw * 16 + ul;
        #pragma unroll
        for (int p = 0; p < 2; ++p) { hd[p][0][hdix] = 0; hd[p][1][hdix] = 0; }
    }
    // ---- load enc B_hi (kg 8..71, own 64 cols) into LDS ----
    for (int i = tid; i < 4096; i += 512) {       // i = kg8*64 + nc
        const int kg8 = i >> 6, nc = i & 63;
        *(u16x8*)(sBe + i * 8) =
            *(const u16x8*)(BeH + ((size_t)(kg8 + 8) * 2048 + w * 64 + nc) * 8);
    }

    const float encBias = encB[nh * 512 + w * 16 + lr];
    float c = 0.f;                                 // enc c-state: 1 reg/thread

    // =====================================================================
    // encoder: 256 steps, 3 dataflow syncs each (progress-word primitive)
    // =====================================================================
    for (int t = 0; t < 256; ++t) {
        // announce h(t-1) done (t=0: init done) + wait all
        arrive_wait(pC, w, (unsigned)(t + 1), (unsigned)(t + 1), 32);

        // ---- GEMM: z[32 rows][own 64 gate-grouped cols], K=576 ----
        f32x4 acc = {0.f, 0.f, 0.f, 0.f};
        #pragma unroll
        for (int kw = 0; kw < 18; ++kw) {
            const int kg = kw * 4 + l16;
            bf16x8 a_h, a_l;
            if (kw < 2) {                          // x part, fp32 -> hi/lo
                const float* xp = x + (size_t)grow * 16384 + t * 64 + kg * 8;
                const float4 x0 = *(const float4*)xp;
                const float4 x1 = *(const float4*)(xp + 4);
                const float xs[8] = {x0.x, x0.y, x0.z, x0.w, x1.x, x1.y, x1.z, x1.w};
                #pragma unroll
                for (int j = 0; j < 8; ++j) {
                    unsigned short hh, ll; split2(xs[j], hh, ll);
                    a_h[j] = (short)hh; a_l[j] = (short)ll;
                }
            } else {                               // h part (global, L2)
                const size_t ao = (size_t)grow * 512 + (size_t)(kg - 8) * 8;
                a_h = *(const bf16x8*)(hEHu + ao);
                a_l = *(const bf16x8*)(hELu + ao);
            }
            bf16x8 b_h;
            if (kw < 2) b_h = *(const bf16x8*)(BeH + ((size_t)kg * 2048 + gcolp) * 8);
            else        b_h = *(const bf16x8*)(sBe + ((kg - 8) * 64 + ncl) * 8);
            const bf16x8 b_l = *(const bf16x8*)(BeL + ((size_t)kg * 2048 + gcolp) * 8);
            acc = __builtin_amdgcn_mfma_f32_16x16x32_bf16(a_h, b_h, acc, 0, 0, 0);
            acc = __builtin_amdgcn_mfma_f32_16x16x32_bf16(a_h, b_l, acc, 0, 0, 0);
            acc = __builtin_amdgcn_mfma_f32_16x16x32_bf16(a_l, b_h, acc, 0, 0, 0);
        }
        #pragma unroll
        for (int r = 0; r < 4; ++r)
            zt[ncl * 33 + mh * 16 + l16 * 4 + r] = acc[r] + encBias;
        __syncthreads();

        // ---- stats-g partials (thread = (urow, ul)) ----
        const float zg = zt[(32 + ul) * 33 + urow];
        {
            const float mw = red16max(zg);
            const float sw = red16sum(__expf(zg - mw));
            if (ul == 0) *(float2*)(pst1 + (urow * 32 + w) * 2) = float2{mw, sw};
        }
        arrive_wait(pA, w, (unsigned)(t + 1), (unsigned)(t + 1), 32);

        // ---- combine g-stats; c update ----
        float M, S;
        {
            const float2 pa = *(const float2*)(pst1 + (urow * 32 + ul) * 2);
            const float2 pb = *(const float2*)(pst1 + (urow * 32 + ul + 16) * 2);
            const float ml = fmaxf(pa.x, pb.x);
            const float sl = pa.y * __expf(pa.x - ml) + pb.y * __expf(pb.x - ml);
            M = red16max(ml);
            S = red16sum(sl * __expf(ml - M));
        }
        const float zi = zt[ul * 33 + urow];
        const float zf = zt[(16 + ul) * 33 + urow];
        c = sigm(zf) * c + sigm(zi) * (__expf(zg - M) / S);

        // ---- stats-c partials ----
        {
            const float m2 = red16max(c);
            const float s2 = red16sum(__expf(c - m2));
            if (ul == 0) *(float2*)(pst2 + (urow * 32 + w) * 2) = float2{m2, s2};
        }
        arrive_wait(pB, w, (unsigned)(t + 1), (unsigned)(t + 1), 32);

        // ---- combine c-stats; h write (own 16-unit slice only) ----
        {
            const float2 pa = *(const float2*)(pst2 + (urow * 32 + ul) * 2);
            const float2 pb = *(const float2*)(pst2 + (urow * 32 + ul + 16) * 2);
            const float ml = fmaxf(pa.x, pb.x);
            const float sl = pa.y * __expf(pa.x - ml) + pb.y * __expf(pb.x - ml);
            const float M2 = red16max(ml);
            const float S2 = red16sum(sl * __expf(ml - M2));
            const float zo = zt[(48 + ul) * 33 + urow];
            const float hv = sigm(zo) * __expf(c - M2) / S2;
            unsigned short hh, hl; split2(hv, hh, hl);
            const size_t he = (size_t)(g * 32 + urow) * 512 + w * 16 + ul;
            hEHu[he] = hh;
            hELu[he] = hl;
        }
    }
    // final h(255) published + wait all
    arrive_wait(pC, w, 257u, 257u, 32);

    // =====================================================================
    // decoder input projection: xw[rows][own 64 cols] (self-consumed)
    // =====================================================================
    {
        const float bias = (dir ? dbB : dfB)[nh * 256 + bw * 16 + lr];
        f32x4 acc = {0.f, 0.f, 0.f, 0.f};
        #pragma unroll
        for (int kw = 0; kw < 16; ++kw) {
            const int kg = kw * 4 + l16;           // 0..63
            const size_t ao = (size_t)grow * 512 + (size_t)kg * 8;
            const bf16x8 a_h = *(const bf16x8*)(hEHu + ao);
            const bf16x8 a_l = *(const bf16x8*)(hELu + ao);
            const size_t bo = ((size_t)kg * 2048 + gcolp) * 8;
            const bf16x8 b_h = *(const bf16x8*)(BkH + bo);
            const bf16x8 b_l = *(const bf16x8*)(BkL + bo);
            acc = __builtin_amdgcn_mfma_f32_16x16x32_bf16(a_h, b_h, acc, 0, 0, 0);
            acc = __builtin_amdgcn_mfma_f32_16x16x32_bf16(a_h, b_l, acc, 0, 0, 0);
            acc = __builtin_amdgcn_mfma_f32_16x16x32_bf16(a_l, b_h, acc, 0, 0, 0);
        }
        float* xp = xw + (size_t)(g * 32 + mh * 16 + l16 * 4) * 2048 + gcolp;
        #pragma unroll
        for (int r = 0; r < 4; ++r) xp[2048 * r] = acc[r] + bias;
    }
    asm volatile("s_waitcnt vmcnt(0)" ::: "memory");
    __syncthreads();                               // xw visible block-locally

    // ---- load dec B_hi (32 kg x own 64 cols) into LDS ----
    for (int i = tid; i < 2048; i += 512) {        // i = kg*64 + nc
        const int kg = i >> 6, nc = i & 63;
        *(u16x8*)(sBe + i * 8) =
            *(const u16x8*)(BuH + ((size_t)kg * 2048 + w * 64 + nc) * 8);
    }
    __syncthreads();

    // =====================================================================
    // decoder: 64 steps, 1 sync each (per-dir, 16 slots); h parity dbuf
    // =====================================================================
    float cd = 0.f;
    const float* xr = xw + (size_t)(g * 32 + urow) * 2048 + w * 64;
    for (int s = 0; s < 64; ++s) {
        if (s) arrive_wait(pD, bw, (unsigned)s, (unsigned)s, 16);
        const int par = s & 1;
        f32x4 acc = {0.f, 0.f, 0.f, 0.f};
        #pragma unroll
        for (int kw = 0; kw < 8; ++kw) {
            const int kg = kw * 4 + l16;           // 0..31
            const size_t ao = (size_t)(g * 32 + lrow) * 256 + (size_t)kg * 8;
            const bf16x8 a_h = *(const bf16x8*)(hd[par][0] + ao);
            const bf16x8 a_l = *(const bf16x8*)(hd[par][1] + ao);
            const bf16x8 b_h = *(const bf16x8*)(sBe + (kg * 64 + ncl) * 8);
            const bf16x8 b_l = *(const bf16x8*)(BuL + ((size_t)kg * 2048 + gcolp) * 8);
            acc = __builtin_amdgcn_mfma_f32_16x16x32_bf16(a_h, b_h, acc, 0, 0, 0);
            acc = __builtin_amdgcn_mfma_f32_16x16x32_bf16(a_h, b_l, acc, 0, 0, 0);
            acc = __builtin_amdgcn_mfma_f32_16x16x32_bf16(a_l, b_h, acc, 0, 0, 0);
        }
        #pragma unroll
        for (int r = 0; r < 4; ++r)
            zt[ncl * 33 + mh * 16 + l16 * 4 + r] = acc[r];
        __syncthreads();

        {   // ---- elementwise gate update: thread owns (urow, unit ul) ----
            const float zi = zt[ul * 33 + urow]        + xr[ul];
            const float zf = zt[(16 + ul) * 33 + urow] + xr[16 + ul];
            const float zg = zt[(32 + ul) * 33 + urow] + xr[32 + ul];
            const float zo = zt[(48 + ul) * 33 + urow] + xr[48 + ul];
            const float cv = sigm(zf) * cd + sigm(zi) * tanhf(zg);
            cd = cv;
            const float hv = sigm(zo) * tanhf(cv);
            unsigned short hh, hl; split2(hv, hh, hl);
            const size_t hdix = (size_t)(g * 32 + urow) * 256 + bw * 16 + ul;
            hd[par ^ 1][0][hdix] = hh;
            hd[par ^ 1][1][hdix] = hl;
            const int tt = dir ? (63 - s) : s;
            hseqb[((size_t)(g * 32 + urow) * 64 + tt) * 512 + dir * 256 + bw * 16 + ul] = hh;
        }
    }
    // hseq complete (both dirs)
    arrive_wait(pE, w, 1u, 1u, 32);

    // =====================================================================
    // dense head: block w -> 64 bt rows of this group's 2048
    // =====================================================================
    {
        float* dkc = (float*)sBe;                  // 32 KB dK cache
        for (int i = tid; i < 8192; i += 512) dkc[i] = dK[i];
        __syncthreads();
        const int f = tid & 15;
        #pragma unroll
        for (int p = 0; p < 2; ++p) {
            const int bt = g * 2048 + w * 64 + (tid >> 4) + p * 32;
            const unsigned short* hs = hseqb + (size_t)bt * 512;
            float acc = dnB[f];
            #pragma unroll 4
            for (int k = 0; k < 512; k += 8) {
                const u16x8 hv = *(const u16x8*)(hs + k);
                #pragma unroll
                for (int j = 0; j < 8; ++j)
                    acc += bf2f(hv[j]) * dkc[(k + j) * 16 + f];
            }
            out[(size_t)bt * 16 + f] = acc;
        }
    }
}

// ---------------------------------------------------------------------------
extern "C" void kernel_launch(void* const* d_in, const int* in_sizes, int n_in,
                              void* d_out, int out_size, void* d_ws, size_t ws_size,
                              hipStream_t stream)
{
    const float* x    = (const float*)d_in[0];
    const float* encW = (const float*)d_in[1];
    const float* encU = (const float*)d_in[2];
    const float* encB = (const float*)d_in[3];
    const float* dfK  = (const float*)d_in[4];
    const float* dfU  = (const float*)d_in[5];
    const float* dfB  = (const float*)d_in[6];
    const float* dbK  = (const float*)d_in[7];
    const float* dbU  = (const float*)d_in[8];
    const float* dbB  = (const float*)d_in[9];
    const float* dK   = (const float*)d_in[10];
    const float* dnB  = (const float*)d_in[11];

    if (ws_size < WS_FLOATS * sizeof(float)) return;

    float* ws = (float*)d_ws;
    unsigned short* BencH = (unsigned short*)(ws + OFS_BENCH);
    unsigned short* BencL = (unsigned short*)(ws + OFS_BENCL);
    unsigned short* BdkH  = (unsigned short*)(ws + OFS_BDKH);
    unsigned short* BdkL  = (unsigned short*)(ws + OFS_BDKL);
    unsigned short* BduH  = (unsigned short*)(ws + OFS_BDUH);
    unsigned short* BduL  = (unsigned short*)(ws + OFS_BDUL);
    unsigned* bar = (unsigned*)(ws + OFS_BAR);

    // one-time weight packs (pack_b<0> re-inits all progress words per replay)
    pack_b<0><<<576, 256, 0, stream>>>(encW, encU, BencH, BencL, bar);
    pack_b<1><<<512, 256, 0, stream>>>(dfK, dbK, BdkH, BdkL, nullptr);
    pack_b<2><<<256, 256, 0, stream>>>(dfU, dbU, BduH, BduL, nullptr);

    // persistent kernel: whole network, XCD-local dataflow sync only
    lstm_all<<<256, 512, 0, stream>>>(x, encB, dfB, dbB, dK, dnB,
                                      (float*)d_out, ws);
}

// Round 12
// 3800.131 us; speedup vs baseline: 1.1032x; 1.1032x over previous
//
#include <hip/hip_runtime.h>
#include <math.h>

// ---------------------------------------------------------------------------
// LSTM encoder-decoder, 3-term bf16 MFMA (hi/lo split), persistent kernel.
// 8 XCD-local groups (bid&7), 32 blocks x 512 thr each, own 32 batch rows.
// Gate-grouped columns (r9-proven). ENCODER r12: 2 syncs/step (was 3) via
// unnormalized-h̃ factorization: publish h̃=sigm(zo)*exp(c) + pst2 partials in
// one publish; consumers fold the per-row scalar exp(-M2)/S2 into the GEMM
// output (z_h = scale_row * (h̃@U); exact-math identical). Sync = AGENT-scope
// store+gather (r10-proven correct; r11's workgroup-scope FAILED correctness),
// split arrive/wait to hide latency under x-GEMM and sigmoid precompute.
// ---------------------------------------------------------------------------

typedef __attribute__((ext_vector_type(8))) short bf16x8;
typedef __attribute__((ext_vector_type(8))) unsigned short u16x8;
typedef __attribute__((ext_vector_type(4))) float f32x4;

// ws layout (float offsets)
#define OFS_XW     0u          // 256*2048 f32 (gate-grouped, block-self-consumed)
#define OFS_HEH    524288u     // enc h̃ hi: 256*512 bf16 (=65536 f)
#define OFS_HEL    589824u
#define OFS_HD     655360u     // dec h: [par2][dir2][hi/lo][256*256 bf16=32768f]
#define OFS_HSEQ   917504u     // 256*64*512 bf16 (=4194304 f)
#define OFS_BENCH  5111808u    // 72*2048*8 bf16 packed (gate-grouped cols)
#define OFS_BENCL  5701632u
#define OFS_BDKH   6291456u    // 64*2048*8
#define OFS_BDKL   6815744u
#define OFS_BDUH   7340032u    // 32*2048*8
#define OFS_BDUL   7602176u
#define OFS_PST    7864320u    // pst1: 8g*32row*32w*2f =16384; pst2: +16384
#define OFS_BAR    7897088u    // 40960 u32: per g 5120: A+0 B+1024 C+2048
                               //   D0+3072 D1+3584 E+4096 (slots stride 32)
#define WS_FLOATS  7938048u    // ~31.8 MB

__device__ __forceinline__ unsigned short bf_hi(float f) {
    union { float f; unsigned u; } v; v.f = f;
    unsigned r = v.u + 0x7fffu + ((v.u >> 16) & 1u);
    return (unsigned short)(r >> 16);
}
__device__ __forceinline__ float bf2f(unsigned short h) {
    union { unsigned u; float f; } v; v.u = ((unsigned)h) << 16;
    return v.f;
}
__device__ __forceinline__ void split2(float f, unsigned short& hi, unsigned short& lo) {
    hi = bf_hi(f);
    lo = bf_hi(f - bf2f(hi));
}
__device__ __forceinline__ float sigm(float x) { return 1.0f / (1.0f + __expf(-x)); }

// ---- split sync: per-block progress words, AGENT scope (r10-proven) -------
__device__ __forceinline__ void arrive_pub(unsigned* arr, int slot, unsigned val) {
    asm volatile("s_waitcnt vmcnt(0) lgkmcnt(0)" ::: "memory");  // publish data
    __syncthreads();
    if (threadIdx.x == 0)
        __hip_atomic_store(arr + slot * 32, val, __ATOMIC_RELAXED,
                           __HIP_MEMORY_SCOPE_AGENT);
}
__device__ __forceinline__ void wait_min(unsigned* arr, unsigned tgt, int nslots) {
    if (threadIdx.x < 64) {
        const int idx = ((int)threadIdx.x < nslots) ? (int)threadIdx.x : 0;
        const long long t0 = clock64();
        for (;;) {
            unsigned v = __hip_atomic_load(arr + idx * 32, __ATOMIC_RELAXED,
                                           __HIP_MEMORY_SCOPE_AGENT);
            #pragma unroll
            for (int m = 32; m; m >>= 1) {
                const unsigned o = (unsigned)__shfl_xor((int)v, m, 64);
                v = (o < v) ? o : v;
            }
            if (v >= tgt) break;
            __builtin_amdgcn_s_sleep(1);
            if (clock64() - t0 > 4000000LL) break;   // deadlock guard only
        }
        asm volatile("buffer_inv sc0" ::: "memory"); // L1 invalidate only
    }
    __syncthreads();
}

// 16-lane-span reductions
__device__ __forceinline__ float red16max(float v) {
    #pragma unroll
    for (int m = 8; m; m >>= 1) v = fmaxf(v, __shfl_xor(v, m, 64));
    return v;
}
__device__ __forceinline__ float red16sum(float v) {
    #pragma unroll
    for (int m = 8; m; m >>= 1) v += __shfl_xor(v, m, 64);
    return v;
}

// ---------------------------------------------------------------------------
// weight pack: fp32 -> bf16 hi/lo, frag layout [kg][2048 packed cols][8]
// GATE-GROUPED packed col n: w=n>>6, gate=(n>>4)&3, ul=n&15.
// MODE 0 also zero-initializes the 40960 barrier words (replay-safe).
// ---------------------------------------------------------------------------
template <int MODE>
__global__ __launch_bounds__(256) void pack_b(
    const float* __restrict__ S0, const float* __restrict__ S1,
    unsigned short* __restrict__ H, unsigned short* __restrict__ L,
    unsigned* __restrict__ bar)
{
    const int idx = blockIdx.x * 256 + threadIdx.x;
    if (MODE == 0 && idx < 40960) bar[idx] = 0u;
    const int n = idx & 2047, kg = idx >> 11;
    int sc;
    const float* Sd;
    if (MODE == 0) {
        sc = ((n >> 4) & 3) * 512 + (n >> 6) * 16 + (n & 15);
        Sd = nullptr;
    } else {
        const int dir = n >> 10, bw = (n >> 6) & 15;
        sc = ((n >> 4) & 3) * 256 + bw * 16 + (n & 15);
        Sd = dir ? S1 : S0;
    }
    u16x8 h8, l8;
    #pragma unroll
    for (int j = 0; j < 8; ++j) {
        const int k = kg * 8 + j;
        float v;
        if (MODE == 0) v = (k < 64) ? S0[(size_t)k * 2048 + sc] : S1[(size_t)(k - 64) * 2048 + sc];
        else           v = Sd[(size_t)k * 1024 + sc];
        unsigned short hh, ll; split2(v, hh, ll);
        h8[j] = hh; l8[j] = ll;
    }
    *(u16x8*)(H + (size_t)idx * 8) = h8;
    *(u16x8*)(L + (size_t)idx * 8) = l8;
}

// ===========================================================================
// Persistent kernel. 256 blocks x 512 thr (8 waves), LDS ~74KB.
// g=bid&7 (XCD), w=bid>>3 (0..31).
// ===========================================================================
__global__ __launch_bounds__(512, 2) void lstm_all(
    const float* __restrict__ x, const float* __restrict__ encB,
    const float* __restrict__ dfB, const float* __restrict__ dbB,
    const float* __restrict__ dK, const float* __restrict__ dnB,
    float* __restrict__ out, float* __restrict__ ws)
{
    const int bid = blockIdx.x, tid = threadIdx.x;
    const int g = bid & 7, w = bid >> 3;          // group (XCD), slot 0..31
    const int lane = tid & 63, wid = tid >> 6;
    const int mh = wid & 1, nh = wid >> 1;        // 2 x 4 wave grid; nh = gate
    const int l16 = lane >> 4, lr = lane & 15;
    const int lrow = mh * 16 + lr;                // local A row
    const int grow = g * 32 + lrow;               // global batch row
    const int ncl  = nh * 16 + lr;                // block-local col 0..63
    const int gcolp = w * 64 + ncl;               // packed global col
    const int urow = tid >> 4, ul = tid & 15;     // update ids: row, unit

    float* xw = ws + OFS_XW;
    unsigned short* hEHu = (unsigned short*)(ws + OFS_HEH);   // h̃ hi
    unsigned short* hELu = (unsigned short*)(ws + OFS_HEL);   // h̃ lo
    unsigned short* hseqb = (unsigned short*)(ws + OFS_HSEQ);
    const unsigned short* BeH = (const unsigned short*)(ws + OFS_BENCH);
    const unsigned short* BeL = (const unsigned short*)(ws + OFS_BENCL);
    const unsigned short* BkH = (const unsigned short*)(ws + OFS_BDKH);
    const unsigned short* BkL = (const unsigned short*)(ws + OFS_BDKL);
    const unsigned short* BuH = (const unsigned short*)(ws + OFS_BDUH);
    const unsigned short* BuL = (const unsigned short*)(ws + OFS_BDUL);
    float* pst1 = ws + OFS_PST + (unsigned)g * 2048u;
    float* pst2 = ws + OFS_PST + 16384u + (unsigned)g * 2048u;
    unsigned* barg = (unsigned*)(ws + OFS_BAR) + g * 5120;
    unsigned* pA = barg + 0;
    unsigned* pB = barg + 1024;
    unsigned* pC = barg + 2048;    // init sync
    unsigned* pE = barg + 4096;

    // LDS: B_hi slice (enc kg 8..71) 64KB + zt [64][33] + scl[32]
    __shared__ __align__(16) unsigned short sBe[32768];
    __shared__ __align__(16) float zt[2112];
    __shared__ float scl[32];

    const int dir = w >> 4, bw = w & 15;
    unsigned* pD = barg + 3072 + dir * 512;
    unsigned short* hd[2][2];
    #pragma unroll
    for (int p = 0; p < 2; ++p)
        #pragma unroll
        for (int hl_ = 0; hl_ < 2; ++hl_)
            hd[p][hl_] = (unsigned short*)(ws + OFS_HD +
                          (unsigned)((p * 2 + dir) * 2 + hl_) * 32768u);

    // ---- init: zero own h slices; pst2 := (m=0, s=1) -> scale 1 ----
    {
        const size_t he = (size_t)(g * 32 + urow) * 512 + w * 16 + ul;
        hEHu[he] = 0; hELu[he] = 0;
        const size_t hdix = (size_t)(g * 32 + urow) * 256 + bw * 16 + ul;
        #pragma unroll
        for (int p = 0; p < 2; ++p) { hd[p][0][hdix] = 0; hd[p][1][hdix] = 0; }
        if (ul == 0) *(float2*)(pst2 + (urow * 32 + w) * 2) = float2{0.f, 1.f};
    }
    // ---- load enc B_hi (kg 8..71, own 64 cols) into LDS ----
    for (int i = tid; i < 4096; i += 512) {       // i = kg8*64 + nc
        const int kg8 = i >> 6, nc = i & 63;
        *(u16x8*)(sBe + i * 8) =
            *(const u16x8*)(BeH + ((size_t)(kg8 + 8) * 2048 + w * 64 + nc) * 8);
    }
    arrive_pub(pC, w, 1u);                        // init published

    const float encBias = encB[nh * 512 + w * 16 + lr];
    float c = 0.f;                                // enc c-state: 1 reg/thread

    // =====================================================================
    // encoder: 256 steps, TWO syncs each (pA: stats1; pB: h̃+stats2)
    // =====================================================================
    for (int t = 0; t < 256; ++t) {
        // ---- x-part GEMM (independent of h̃) ----
        f32x4 ax = {0.f, 0.f, 0.f, 0.f};
        #pragma unroll
        for (int kw = 0; kw < 2; ++kw) {
            const int kg = kw * 4 + l16;          // 0..7
            const float* xp = x + (size_t)grow * 16384 + t * 64 + kg * 8;
            const float4 x0 = *(const float4*)xp;
            const float4 x1 = *(const float4*)(xp + 4);
            const float xs[8] = {x0.x, x0.y, x0.z, x0.w, x1.x, x1.y, x1.z, x1.w};
            bf16x8 a_h, a_l;
            #pragma unroll
            for (int j = 0; j < 8; ++j) {
                unsigned short hh, ll; split2(xs[j], hh, ll);
                a_h[j] = (short)hh; a_l[j] = (short)ll;
            }
            const size_t bo = ((size_t)kg * 2048 + gcolp) * 8;
            const bf16x8 b_h = *(const bf16x8*)(BeH + bo);
            const bf16x8 b_l = *(const bf16x8*)(BeL + bo);
            ax = __builtin_amdgcn_mfma_f32_16x16x32_bf16(a_h, b_h, ax, 0, 0, 0);
            ax = __builtin_amdgcn_mfma_f32_16x16x32_bf16(a_h, b_l, ax, 0, 0, 0);
            ax = __builtin_amdgcn_mfma_f32_16x16x32_bf16(a_l, b_h, ax, 0, 0, 0);
        }
        // ---- wait h̃(t-1)+pst2(t-1) ready ----
        if (t == 0) wait_min(pC, 1u, 32);
        else        wait_min(pB, (unsigned)t, 32);

        // ---- per-row scale from pst2 -> LDS ----
        {
            const float2 pa = *(const float2*)(pst2 + (urow * 32 + ul) * 2);
            const float2 pb = *(const float2*)(pst2 + (urow * 32 + ul + 16) * 2);
            const float ml = fmaxf(pa.x, pb.x);
            const float sl = pa.y * __expf(pa.x - ml) + pb.y * __expf(pb.x - ml);
            const float M2 = red16max(ml);
            const float S2 = red16sum(sl * __expf(ml - M2));
            if (ul == 0) scl[urow] = __expf(-M2) / S2;
        }
        __syncthreads();

        // ---- h̃-part GEMM (K=512), then z = scale*acc_h + acc_x + bias ----
        f32x4 ah = {0.f, 0.f, 0.f, 0.f};
        #pragma unroll
        for (int kw = 2; kw < 18; ++kw) {
            const int kg = kw * 4 + l16;          // 8..71
            const size_t ao = (size_t)grow * 512 + (size_t)(kg - 8) * 8;
            const bf16x8 a_h = *(const bf16x8*)(hEHu + ao);
            const bf16x8 a_l = *(const bf16x8*)(hELu + ao);
            const bf16x8 b_h = *(const bf16x8*)(sBe + ((kg - 8) * 64 + ncl) * 8);
            const bf16x8 b_l = *(const bf16x8*)(BeL + ((size_t)kg * 2048 + gcolp) * 8);
            ah = __builtin_amdgcn_mfma_f32_16x16x32_bf16(a_h, b_h, ah, 0, 0, 0);
            ah = __builtin_amdgcn_mfma_f32_16x16x32_bf16(a_h, b_l, ah, 0, 0, 0);
            ah = __builtin_amdgcn_mfma_f32_16x16x32_bf16(a_l, b_h, ah, 0, 0, 0);
        }
        #pragma unroll
        for (int r = 0; r < 4; ++r) {
            const int row = mh * 16 + l16 * 4 + r;
            zt[ncl * 33 + row] = scl[row] * ah[r] + ax[r] + encBias;
        }
        __syncthreads();

        // ---- stats-g partials; publish; sigmoids hidden under pA wait ----
        const float zg = zt[(32 + ul) * 33 + urow];
        {
            const float mw = red16max(zg);
            const float sw = red16sum(__expf(zg - mw));
            if (ul == 0) *(float2*)(pst1 + (urow * 32 + w) * 2) = float2{mw, sw};
        }
        arrive_pub(pA, w, (unsigned)(t + 1));
        const float zi = zt[ul * 33 + urow];
        const float zf = zt[(16 + ul) * 33 + urow];
        const float zo = zt[(48 + ul) * 33 + urow];
        const float si = sigm(zi), sf = sigm(zf), so = sigm(zo);
        wait_min(pA, (unsigned)(t + 1), 32);

        // ---- combine stats1; c update; publish h̃ + stats2 ----
        {
            const float2 pa = *(const float2*)(pst1 + (urow * 32 + ul) * 2);
            const float2 pb = *(const float2*)(pst1 + (urow * 32 + ul + 16) * 2);
            const float ml = fmaxf(pa.x, pb.x);
            const float sl = pa.y * __expf(pa.x - ml) + pb.y * __expf(pb.x - ml);
            const float M = red16max(ml);
            const float S = red16sum(sl * __expf(ml - M));
            c = sf * c + si * (__expf(zg - M) / S);
        }
        {
            const float ht = so * __expf(c);      // unnormalized h̃
            unsigned short hh, hl; split2(ht, hh, hl);
            const size_t he = (size_t)(g * 32 + urow) * 512 + w * 16 + ul;
            hEHu[he] = hh;
            hELu[he] = hl;
            const float m2 = red16max(c);
            const float s2 = red16sum(__expf(c - m2));
            if (ul == 0) *(float2*)(pst2 + (urow * 32 + w) * 2) = float2{m2, s2};
        }
        arrive_pub(pB, w, (unsigned)(t + 1));
    }
    wait_min(pB, 256u, 32);                       // final h̃(255)+pst2(255)

    // =====================================================================
    // decoder input projection: xw = scale_row*(h̃ @ Bdk) + bias
    // =====================================================================
    {
        const float2 pa = *(const float2*)(pst2 + (urow * 32 + ul) * 2);
        const float2 pb = *(const float2*)(pst2 + (urow * 32 + ul + 16) * 2);
        const float ml = fmaxf(pa.x, pb.x);
        const float sl = pa.y * __expf(pa.x - ml) + pb.y * __expf(pb.x - ml);
        const float M2 = red16max(ml);
        const float S2 = red16sum(sl * __expf(ml - M2));
        if (ul == 0) scl[urow] = __expf(-M2) / S2;
    }
    __syncthreads();
    {
        const float bias = (dir ? dbB : dfB)[nh * 256 + bw * 16 + lr];
        f32x4 acc = {0.f, 0.f, 0.f, 0.f};
        #pragma unroll
        for (int kw = 0; kw < 16; ++kw) {
            const int kg = kw * 4 + l16;           // 0..63
            const size_t ao = (size_t)grow * 512 + (size_t)kg * 8;
            const bf16x8 a_h = *(const bf16x8*)(hEHu + ao);
            const bf16x8 a_l = *(const bf16x8*)(hELu + ao);
            const size_t bo = ((size_t)kg * 2048 + gcolp) * 8;
            const bf16x8 b_h = *(const bf16x8*)(BkH + bo);
            const bf16x8 b_l = *(const bf16x8*)(BkL + bo);
            acc = __builtin_amdgcn_mfma_f32_16x16x32_bf16(a_h, b_h, acc, 0, 0, 0);
            acc = __builtin_amdgcn_mfma_f32_16x16x32_bf16(a_h, b_l, acc, 0, 0, 0);
            acc = __builtin_amdgcn_mfma_f32_16x16x32_bf16(a_l, b_h, acc, 0, 0, 0);
        }
        float* xp = xw + (size_t)(g * 32 + mh * 16 + l16 * 4) * 2048 + gcolp;
        #pragma unroll
        for (int r = 0; r < 4; ++r) {
            const int row = mh * 16 + l16 * 4 + r;
            xp[2048 * r] = scl[row] * acc[r] + bias;
        }
    }
    asm volatile("s_waitcnt vmcnt(0)" ::: "memory");
    __syncthreads();                               // xw visible block-locally

    // ---- load dec B_hi (32 kg x own 64 cols) into LDS ----
    for (int i = tid; i < 2048; i += 512) {        // i = kg*64 + nc
        const int kg = i >> 6, nc = i & 63;
        *(u16x8*)(sBe + i * 8) =
            *(const u16x8*)(BuH + ((size_t)kg * 2048 + w * 64 + nc) * 8);
    }
    __syncthreads();

    // =====================================================================
    // decoder: 64 steps, 1 sync each (per-dir, 16 slots); h parity dbuf
    // =====================================================================
    float cd = 0.f;
    const float* xr = xw + (size_t)(g * 32 + urow) * 2048 + w * 64;
    for (int s = 0; s < 64; ++s) {
        if (s) { arrive_pub(pD, bw, (unsigned)s); wait_min(pD, (unsigned)s, 16); }
        const int par = s & 1;
        f32x4 acc = {0.f, 0.f, 0.f, 0.f};
        #pragma unroll
        for (int kw = 0; kw < 8; ++kw) {
            const int kg = kw * 4 + l16;           // 0..31
            const size_t ao = (size_t)(g * 32 + lrow) * 256 + (size_t)kg * 8;
            const bf16x8 a_h = *(const bf16x8*)(hd[par][0] + ao);
            const bf16x8 a_l = *(const bf16x8*)(hd[par][1] + ao);
            const bf16x8 b_h = *(const bf16x8*)(sBe + (kg * 64 + ncl) * 8);
            const bf16x8 b_l = *(const bf16x8*)(BuL + ((size_t)kg * 2048 + gcolp) * 8);
            acc = __builtin_amdgcn_mfma_f32_16x16x32_bf16(a_h, b_h, acc, 0, 0, 0);
            acc = __builtin_amdgcn_mfma_f32_16x16x32_bf16(a_h, b_l, acc, 0, 0, 0);
            acc = __builtin_amdgcn_mfma_f32_16x16x32_bf16(a_l, b_h, acc, 0, 0, 0);
        }
        #pragma unroll
        for (int r = 0; r < 4; ++r)
            zt[ncl * 33 + mh * 16 + l16 * 4 + r] = acc[r];
        __syncthreads();

        {   // ---- elementwise gate update: thread owns (urow, unit ul) ----
            const float zi = zt[ul * 33 + urow]        + xr[ul];
            const float zf = zt[(16 + ul) * 33 + urow] + xr[16 + ul];
            const float zg = zt[(32 + ul) * 33 + urow] + xr[32 + ul];
            const float zo = zt[(48 + ul) * 33 + urow] + xr[48 + ul];
            const float cv = sigm(zf) * cd + sigm(zi) * tanhf(zg);
            cd = cv;
            const float hv = sigm(zo) * tanhf(cv);
            unsigned short hh, hl; split2(hv, hh, hl);
            const size_t hdix = (size_t)(g * 32 + urow) * 256 + bw * 16 + ul;
            hd[par ^ 1][0][hdix] = hh;
            hd[par ^ 1][1][hdix] = hl;
            const int tt = dir ? (63 - s) : s;
            hseqb[((size_t)(g * 32 + urow) * 64 + tt) * 512 + dir * 256 + bw * 16 + ul] = hh;
        }
        __syncthreads();
    }
    arrive_pub(pE, w, 1u); wait_min(pE, 1u, 32);   // hseq complete (both dirs)

    // =====================================================================
    // dense head: block w -> 64 bt rows of this group's 2048
    // =====================================================================
    {
        float* dkc = (float*)sBe;                  // 32 KB dK cache
        for (int i = tid; i < 8192; i += 512) dkc[i] = dK[i];
        __syncthreads();
        const int f = tid & 15;
        #pragma unroll
        for (int p = 0; p < 2; ++p) {
            const int bt = g * 2048 + w * 64 + (tid >> 4) + p * 32;
            const unsigned short* hs = hseqb + (size_t)bt * 512;
            float acc = dnB[f];
            #pragma unroll 4
            for (int k = 0; k < 512; k += 8) {
                const u16x8 hv = *(const u16x8*)(hs + k);
                #pragma unroll
                for (int j = 0; j < 8; ++j)
                    acc += bf2f(hv[j]) * dkc[(k + j) * 16 + f];
            }
            out[(size_t)bt * 16 + f] = acc;
        }
    }
}

// ---------------------------------------------------------------------------
extern "C" void kernel_launch(void* const* d_in, const int* in_sizes, int n_in,
                              void* d_out, int out_size, void* d_ws, size_t ws_size,
                              hipStream_t stream)
{
    const float* x    = (const float*)d_in[0];
    const float* encW = (const float*)d_in[1];
    const float* encU = (const float*)d_in[2];
    const float* encB = (const float*)d_in[3];
    const float* dfK  = (const float*)d_in[4];
    const float* dfU  = (const float*)d_in[5];
    const float* dfB  = (const float*)d_in[6];
    const float* dbK  = (const float*)d_in[7];
    const float* dbU  = (const float*)d_in[8];
    const float* dbB  = (const float*)d_in[9];
    const float* dK   = (const float*)d_in[10];
    const float* dnB  = (const float*)d_in[11];

    if (ws_size < WS_FLOATS * sizeof(float)) return;

    float* ws = (float*)d_ws;
    unsigned short* BencH = (unsigned short*)(ws + OFS_BENCH);
    unsigned short* BencL = (unsigned short*)(ws + OFS_BENCL);
    unsigned short* BdkH  = (unsigned short*)(ws + OFS_BDKH);
    unsigned short* BdkL  = (unsigned short*)(ws + OFS_BDKL);
    unsigned short* BduH  = (unsigned short*)(ws + OFS_BDUH);
    unsigned short* BduL  = (unsigned short*)(ws + OFS_BDUL);
    unsigned* bar = (unsigned*)(ws + OFS_BAR);

    // one-time weight packs (pack_b<0> re-inits all progress words per replay)
    pack_b<0><<<576, 256, 0, stream>>>(encW, encU, BencH, BencL, bar);
    pack_b<1><<<512, 256, 0, stream>>>(dfK, dbK, BdkH, BdkL, nullptr);
    pack_b<2><<<256, 256, 0, stream>>>(dfU, dbU, BduH, BduL, nullptr);

    // persistent kernel: whole network, XCD-local dataflow sync only
    lstm_all<<<256, 512, 0, stream>>>(x, encB, dfB, dbB, dK, dnB,
                                      (float*)d_out, ws);
}

// Round 13
// 2619.116 us; speedup vs baseline: 1.6006x; 1.4509x over previous
//
#include <hip/hip_runtime.h>
#include <math.h>

// ---------------------------------------------------------------------------
// LSTM encoder-decoder, 3-term bf16 MFMA (hi/lo split), persistent kernel.
// 8 XCD-local groups (bid&7), 32 blocks x 512 thr each, own 32 batch rows.
// Gate-grouped columns (r9/r12-proven). r13: TWO INDEPENDENT HALF-CHAINS per
// block (rows 0-15 = waves 0-3, rows 16-31 = waves 4-7), each with its own
// progress words + sub-block LDS barriers (no __syncthreads in enc loop).
// While one half spins on the cross-block AGENT-scope sync, the other half's
// waves use the CU -> sync latency hides under compute. h̃ stored in
// MFMA-fragment-packed layout [kg][row][8] for fully-coalesced A-loads.
// ---------------------------------------------------------------------------

typedef __attribute__((ext_vector_type(8))) short bf16x8;
typedef __attribute__((ext_vector_type(8))) unsigned short u16x8;
typedef __attribute__((ext_vector_type(4))) float f32x4;

// ws layout (float offsets)
#define OFS_XW     0u          // 256*2048 f32
#define OFS_HEH    524288u     // enc h̃ hi PACKED [g][kg64][row32][8] (=65536 f)
#define OFS_HEL    589824u
#define OFS_HD     655360u     // dec h: [par2][dir2][hi/lo][256*256 bf16]
#define OFS_HSEQ   917504u     // 256*64*512 bf16 (=4194304 f)
#define OFS_BENCH  5111808u    // 72*2048*8 bf16 packed (gate-grouped cols)
#define OFS_BENCL  5701632u
#define OFS_BDKH   6291456u    // 64*2048*8
#define OFS_BDKL   6815744u
#define OFS_BDUH   7340032u    // 32*2048*8
#define OFS_BDUL   7602176u
#define OFS_PST    7864320u    // pst1: 8g*32row*32w*2f; pst2: +16384
#define OFS_BAR    7897088u    // 65536 u32, per g 8192: pC+0 pA0+1024 pA1+2048
                               //  pB0+3072 pB1+4096 pD+5120(2x512) pE+6144
#define WS_FLOATS  7962624u    // ~31.9 MB

__device__ __forceinline__ unsigned short bf_hi(float f) {
    union { float f; unsigned u; } v; v.f = f;
    unsigned r = v.u + 0x7fffu + ((v.u >> 16) & 1u);
    return (unsigned short)(r >> 16);
}
__device__ __forceinline__ float bf2f(unsigned short h) {
    union { unsigned u; float f; } v; v.u = ((unsigned)h) << 16;
    return v.f;
}
__device__ __forceinline__ void split2(float f, unsigned short& hi, unsigned short& lo) {
    hi = bf_hi(f);
    lo = bf_hi(f - bf2f(hi));
}
__device__ __forceinline__ float sigm(float x) { return 1.0f / (1.0f + __expf(-x)); }

// ---- cross-block spin (one wave; lanes gather slots; AGENT scope) ---------
__device__ __forceinline__ void gspin(unsigned* arr, unsigned tgt, int nslots) {
    const int lane = threadIdx.x & 63;
    const int idx = (lane < nslots) ? lane : 0;
    const long long t0 = clock64();
    for (;;) {
        unsigned v = __hip_atomic_load(arr + idx * 32, __ATOMIC_RELAXED,
                                       __HIP_MEMORY_SCOPE_AGENT);
        #pragma unroll
        for (int m = 32; m; m >>= 1) {
            const unsigned o = (unsigned)__shfl_xor((int)v, m, 64);
            v = (o < v) ? o : v;
        }
        if (v >= tgt) break;
        __builtin_amdgcn_s_sleep(1);
        if (clock64() - t0 > 4000000LL) break;   // deadlock guard only
    }
    asm volatile("buffer_inv sc0" ::: "memory");  // L1-only invalidate
}

// ---- sub-block LDS barrier (monotonic counter; 4 waves of a half) ---------
#define HB(cnt, tgt) do { \
    asm volatile("s_waitcnt vmcnt(0) lgkmcnt(0)" ::: "memory"); \
    if ((threadIdx.x & 63) == 0) atomicAdd((cnt), 1u); \
    const long long _hb0 = clock64(); \
    while (__hip_atomic_load((cnt), __ATOMIC_RELAXED, \
                             __HIP_MEMORY_SCOPE_WORKGROUP) < (tgt)) { \
        __builtin_amdgcn_s_sleep(0); \
        if (clock64() - _hb0 > 8000000LL) break; } \
    asm volatile("" ::: "memory"); } while (0)

#define LDS_SPIN(ptr, tgt) do { \
    const long long _ls0 = clock64(); \
    while (__hip_atomic_load((ptr), __ATOMIC_RELAXED, \
                             __HIP_MEMORY_SCOPE_WORKGROUP) < (tgt)) { \
        __builtin_amdgcn_s_sleep(0); \
        if (clock64() - _ls0 > 8000000LL) break; } \
    asm volatile("" ::: "memory"); } while (0)

// ---- full-block sync helpers (decoder; r12-proven) ------------------------
__device__ __forceinline__ void arrive_pub(unsigned* arr, int slot, unsigned val) {
    asm volatile("s_waitcnt vmcnt(0) lgkmcnt(0)" ::: "memory");
    __syncthreads();
    if (threadIdx.x == 0)
        __hip_atomic_store(arr + slot * 32, val, __ATOMIC_RELAXED,
                           __HIP_MEMORY_SCOPE_AGENT);
}
__device__ __forceinline__ void wait_min(unsigned* arr, unsigned tgt, int nslots) {
    if (threadIdx.x < 64) gspin(arr, tgt, nslots);
    __syncthreads();
}

// 16-lane-span reductions
__device__ __forceinline__ float red16max(float v) {
    #pragma unroll
    for (int m = 8; m; m >>= 1) v = fmaxf(v, __shfl_xor(v, m, 64));
    return v;
}
__device__ __forceinline__ float red16sum(float v) {
    #pragma unroll
    for (int m = 8; m; m >>= 1) v += __shfl_xor(v, m, 64);
    return v;
}

// ---------------------------------------------------------------------------
// weight pack (r9-proven). MODE 0 zeroes the 65536 barrier words.
// ---------------------------------------------------------------------------
template <int MODE>
__global__ __launch_bounds__(256) void pack_b(
    const float* __restrict__ S0, const float* __restrict__ S1,
    unsigned short* __restrict__ H, unsigned short* __restrict__ L,
    unsigned* __restrict__ bar)
{
    const int idx = blockIdx.x * 256 + threadIdx.x;
    if (MODE == 0 && idx < 65536) bar[idx] = 0u;
    const int n = idx & 2047, kg = idx >> 11;
    int sc;
    const float* Sd;
    if (MODE == 0) {
        sc = ((n >> 4) & 3) * 512 + (n >> 6) * 16 + (n & 15);
        Sd = nullptr;
    } else {
        const int dir = n >> 10, bw = (n >> 6) & 15;
        sc = ((n >> 4) & 3) * 256 + bw * 16 + (n & 15);
        Sd = dir ? S1 : S0;
    }
    u16x8 h8, l8;
    #pragma unroll
    for (int j = 0; j < 8; ++j) {
        const int k = kg * 8 + j;
        float v;
        if (MODE == 0) v = (k < 64) ? S0[(size_t)k * 2048 + sc] : S1[(size_t)(k - 64) * 2048 + sc];
        else           v = Sd[(size_t)k * 1024 + sc];
        unsigned short hh, ll; split2(v, hh, ll);
        h8[j] = hh; l8[j] = ll;
    }
    *(u16x8*)(H + (size_t)idx * 8) = h8;
    *(u16x8*)(L + (size_t)idx * 8) = l8;
}

// ===========================================================================
// Persistent kernel. 256 blocks x 512 thr (8 waves), LDS ~74KB.
// g=bid&7 (XCD), w=bid>>3 (0..31). Waves: half=wid>>2, gate=wid&3.
// ===========================================================================
__global__ __launch_bounds__(512, 2) void lstm_all(
    const float* __restrict__ x, const float* __restrict__ encB,
    const float* __restrict__ dfB, const float* __restrict__ dbB,
    const float* __restrict__ dK, const float* __restrict__ dnB,
    float* __restrict__ out, float* __restrict__ ws)
{
    const int bid = blockIdx.x, tid = threadIdx.x;
    const int g = bid & 7, w = bid >> 3;
    const int lane = tid & 63, wid = tid >> 6;
    const int half = wid >> 2, gate = wid & 3;    // enc wave roles
    const int l16 = lane >> 4, lr = lane & 15;
    const int lrow = half * 16 + lr;              // enc A row (group-local)
    const int grow = g * 32 + lrow;
    const int ncl  = gate * 16 + lr;              // block-local col
    const int gcolp = w * 64 + ncl;               // packed global col
    const int tidh = tid & 255;
    const int urh = tidh >> 4, ul = tidh & 15;    // update ids within half
    const int urow = half * 16 + urh;             // group-local row

    float* xw = ws + OFS_XW;
    unsigned short* hEHu = (unsigned short*)(ws + OFS_HEH);   // packed h̃ hi
    unsigned short* hELu = (unsigned short*)(ws + OFS_HEL);
    unsigned short* hseqb = (unsigned short*)(ws + OFS_HSEQ);
    const unsigned short* BeH = (const unsigned short*)(ws + OFS_BENCH);
    const unsigned short* BeL = (const unsigned short*)(ws + OFS_BENCL);
    const unsigned short* BkH = (const unsigned short*)(ws + OFS_BDKH);
    const unsigned short* BkL = (const unsigned short*)(ws + OFS_BDKL);
    const unsigned short* BuH = (const unsigned short*)(ws + OFS_BDUH);
    const unsigned short* BuL = (const unsigned short*)(ws + OFS_BDUL);
    float* pst1 = ws + OFS_PST + (unsigned)g * 2048u;
    float* pst2 = ws + OFS_PST + 16384u + (unsigned)g * 2048u;
    unsigned* barg = (unsigned*)(ws + OFS_BAR) + g * 8192;
    unsigned* pC = barg;
    unsigned* pAh[2] = {barg + 1024, barg + 2048};
    unsigned* pBh[2] = {barg + 3072, barg + 4096};
    unsigned* pE = barg + 6144;

    __shared__ __align__(16) unsigned short sBe[32768];  // enc B_hi kg 8..71
    __shared__ __align__(16) float zt[2112];             // [64 cols][33]
    __shared__ float scl[32];
    __shared__ unsigned harr[2], hrel[2];

    const int dir = w >> 4, bw = w & 15;
    unsigned* pD = barg + 5120 + dir * 512;
    unsigned short* hd[2][2];
    #pragma unroll
    for (int p = 0; p < 2; ++p)
        #pragma unroll
        for (int hl_ = 0; hl_ < 2; ++hl_)
            hd[p][hl_] = (unsigned short*)(ws + OFS_HD +
                          (unsigned)((p * 2 + dir) * 2 + hl_) * 32768u);

    if (tid < 2) { harr[tid] = 0u; hrel[tid] = 0u; }

    // ---- init: zero own h̃ slice (packed) + dec h; pst2 := (0,1) ----
    {
        const int urow32 = tid >> 4, ul32 = tid & 15;     // full-block ids
        const int u = w * 16 + ul32;
        const size_t he = ((size_t)(g * 64 + (u >> 3)) * 32 + urow32) * 8 + (u & 7);
        hEHu[he] = 0; hELu[he] = 0;
        const size_t hdix = (size_t)(g * 32 + urow32) * 256 + bw * 16 + ul32;
        #pragma unroll
        for (int p = 0; p < 2; ++p) { hd[p][0][hdix] = 0; hd[p][1][hdix] = 0; }
        if (ul32 == 0) *(float2*)(pst2 + (urow32 * 32 + w) * 2) = float2{0.f, 1.f};
    }
    for (int i = tid; i < 4096; i += 512) {       // enc B_hi -> LDS
        const int kg8 = i >> 6, nc = i & 63;
        *(u16x8*)(sBe + i * 8) =
            *(const u16x8*)(BeH + ((size_t)(kg8 + 8) * 2048 + w * 64 + nc) * 8);
    }
    arrive_pub(pC, w, 1u);                        // init published (syncthreads)

    const float encBias = encB[gate * 512 + w * 16 + lr];
    float c = 0.f;

    // =====================================================================
    // encoder: 256 steps; two independent half-chains; NO __syncthreads
    // =====================================================================
    for (int t = 0; t < 256; ++t) {
        // ---- x-part GEMM (no h̃ dependency) ----
        f32x4 ax = {0.f, 0.f, 0.f, 0.f};
        #pragma unroll
        for (int kw = 0; kw < 2; ++kw) {
            const int kg = kw * 4 + l16;
            const float* xp = x + (size_t)grow * 16384 + t * 64 + kg * 8;
            const float4 x0 = *(const float4*)xp;
            const float4 x1 = *(const float4*)(xp + 4);
            const float xs[8] = {x0.x, x0.y, x0.z, x0.w, x1.x, x1.y, x1.z, x1.w};
            bf16x8 a_h, a_l;
            #pragma unroll
            for (int j = 0; j < 8; ++j) {
                unsigned short hh, ll; split2(xs[j], hh, ll);
                a_h[j] = (short)hh; a_l[j] = (short)ll;
            }
            const size_t bo = ((size_t)kg * 2048 + gcolp) * 8;
            const bf16x8 b_h = *(const bf16x8*)(BeH + bo);
            const bf16x8 b_l = *(const bf16x8*)(BeL + bo);
            ax = __builtin_amdgcn_mfma_f32_16x16x32_bf16(a_h, b_h, ax, 0, 0, 0);
            ax = __builtin_amdgcn_mfma_f32_16x16x32_bf16(a_h, b_l, ax, 0, 0, 0);
            ax = __builtin_amdgcn_mfma_f32_16x16x32_bf16(a_l, b_h, ax, 0, 0, 0);
        }
        // ---- half-chain wait: h̃(t-1)+pst2(t-1) from all blocks ----
        if (gate == 0) {
            if (t == 0) gspin(pC, 1u, 32);
            else        gspin(pBh[half], (unsigned)t, 32);
            if (lane == 0) atomicAdd(&hrel[half], 1u);
        }
        LDS_SPIN(&hrel[half], (unsigned)(2 * t + 1));

        // ---- per-row scale from pst2 (own half's rows) ----
        {
            const float2 pa = *(const float2*)(pst2 + (urow * 32 + ul) * 2);
            const float2 pb = *(const float2*)(pst2 + (urow * 32 + ul + 16) * 2);
            const float ml = fmaxf(pa.x, pb.x);
            const float sl = pa.y * __expf(pa.x - ml) + pb.y * __expf(pb.x - ml);
            const float M2 = red16max(ml);
            const float S2 = red16sum(sl * __expf(ml - M2));
            if (ul == 0) scl[urow] = __expf(-M2) / S2;
        }
        HB(&harr[half], 4u * (4 * t + 1));

        // ---- h̃-part GEMM (packed A, coalesced) ----
        f32x4 ah = {0.f, 0.f, 0.f, 0.f};
        #pragma unroll
        for (int kw = 2; kw < 18; ++kw) {
            const int kg = kw * 4 + l16;          // 8..71
            const size_t ao = ((size_t)(g * 64 + (kg - 8)) * 32 + lrow) * 8;
            const bf16x8 a_h = *(const bf16x8*)(hEHu + ao);
            const bf16x8 a_l = *(const bf16x8*)(hELu + ao);
            const bf16x8 b_h = *(const bf16x8*)(sBe + ((kg - 8) * 64 + ncl) * 8);
            const bf16x8 b_l = *(const bf16x8*)(BeL + ((size_t)kg * 2048 + gcolp) * 8);
            ah = __builtin_amdgcn_mfma_f32_16x16x32_bf16(a_h, b_h, ah, 0, 0, 0);
            ah = __builtin_amdgcn_mfma_f32_16x16x32_bf16(a_h, b_l, ah, 0, 0, 0);
            ah = __builtin_amdgcn_mfma_f32_16x16x32_bf16(a_l, b_h, ah, 0, 0, 0);
        }
        #pragma unroll
        for (int r = 0; r < 4; ++r) {
            const int row = half * 16 + l16 * 4 + r;
            zt[ncl * 33 + row] = scl[row] * ah[r] + ax[r] + encBias;
        }
        HB(&harr[half], 4u * (4 * t + 2));        // zt ready

        // ---- stats-g partials + sigmoids ----
        const float zg = zt[(32 + ul) * 33 + urow];
        {
            const float mw = red16max(zg);
            const float sw = red16sum(__expf(zg - mw));
            if (ul == 0) *(float2*)(pst1 + (urow * 32 + w) * 2) = float2{mw, sw};
        }
        const float si = sigm(zt[ul * 33 + urow]);
        const float sf = sigm(zt[(16 + ul) * 33 + urow]);
        const float so = sigm(zt[(48 + ul) * 33 + urow]);
        HB(&harr[half], 4u * (4 * t + 3));        // pst1 drained

        if (gate == 0) {
            if (lane == 0)
                __hip_atomic_store(pAh[half] + w * 32, (unsigned)(t + 1),
                                   __ATOMIC_RELAXED, __HIP_MEMORY_SCOPE_AGENT);
            gspin(pAh[half], (unsigned)(t + 1), 32);
            if (lane == 0) atomicAdd(&hrel[half], 1u);
        }
        LDS_SPIN(&hrel[half], (unsigned)(2 * t + 2));

        // ---- combine stats1; c update; publish h̃ (packed) + stats2 ----
        {
            const float2 pa = *(const float2*)(pst1 + (urow * 32 + ul) * 2);
            const float2 pb = *(const float2*)(pst1 + (urow * 32 + ul + 16) * 2);
            const float ml = fmaxf(pa.x, pb.x);
            const float sl = pa.y * __expf(pa.x - ml) + pb.y * __expf(pb.x - ml);
            const float M = red16max(ml);
            const float S = red16sum(sl * __expf(ml - M));
            c = sf * c + si * (__expf(zg - M) / S);
        }
        {
            const float ht = so * __expf(c);
            unsigned short hh, hl; split2(ht, hh, hl);
            const int u = w * 16 + ul;
            const size_t he = ((size_t)(g * 64 + (u >> 3)) * 32 + urow) * 8 + (u & 7);
            hEHu[he] = hh;
            hELu[he] = hl;
            const float m2 = red16max(c);
            const float s2 = red16sum(__expf(c - m2));
            if (ul == 0) *(float2*)(pst2 + (urow * 32 + w) * 2) = float2{m2, s2};
        }
        HB(&harr[half], 4u * (4 * t + 4));        // h̃+pst2 drained
        if (gate == 0 && lane == 0)
            __hip_atomic_store(pBh[half] + w * 32, (unsigned)(t + 1),
                               __ATOMIC_RELAXED, __HIP_MEMORY_SCOPE_AGENT);
    }

    // ---- rejoin halves; wait all blocks' final h̃ ----
    __syncthreads();
    wait_min(pBh[0], 256u, 32);
    wait_min(pBh[1], 256u, 32);

    // =====================================================================
    // decoder input projection: xw = scale_row*(h̃ @ Bdk) + bias
    // =====================================================================
    {
        const int urow32 = tid >> 4, ul32 = tid & 15;
        const float2 pa = *(const float2*)(pst2 + (urow32 * 32 + ul32) * 2);
        const float2 pb = *(const float2*)(pst2 + (urow32 * 32 + ul32 + 16) * 2);
        const float ml = fmaxf(pa.x, pb.x);
        const float sl = pa.y * __expf(pa.x - ml) + pb.y * __expf(pb.x - ml);
        const float M2 = red16max(ml);
        const float S2 = red16sum(sl * __expf(ml - M2));
        if (ul32 == 0) scl[urow32] = __expf(-M2) / S2;
    }
    __syncthreads();
    const int dmh = wid & 1, dnh = wid >> 1;       // dec wave roles
    const int dlrow = dmh * 16 + lr;
    const int dncl = dnh * 16 + lr;
    const int dgcolp = w * 64 + dncl;
    {
        const float bias = (dir ? dbB : dfB)[dnh * 256 + bw * 16 + lr];
        f32x4 acc = {0.f, 0.f, 0.f, 0.f};
        #pragma unroll
        for (int kw = 0; kw < 16; ++kw) {
            const int kg = kw * 4 + l16;           // 0..63
            const size_t ao = ((size_t)(g * 64 + kg) * 32 + dlrow) * 8;
            const bf16x8 a_h = *(const bf16x8*)(hEHu + ao);
            const bf16x8 a_l = *(const bf16x8*)(hELu + ao);
            const size_t bo = ((size_t)kg * 2048 + dgcolp) * 8;
            const bf16x8 b_h = *(const bf16x8*)(BkH + bo);
            const bf16x8 b_l = *(const bf16x8*)(BkL + bo);
            acc = __builtin_amdgcn_mfma_f32_16x16x32_bf16(a_h, b_h, acc, 0, 0, 0);
            acc = __builtin_amdgcn_mfma_f32_16x16x32_bf16(a_h, b_l, acc, 0, 0, 0);
            acc = __builtin_amdgcn_mfma_f32_16x16x32_bf16(a_l, b_h, acc, 0, 0, 0);
        }
        float* xp = xw + (size_t)(g * 32 + dmh * 16 + l16 * 4) * 2048 + dgcolp;
        #pragma unroll
        for (int r = 0; r < 4; ++r) {
            const int prow = dmh * 16 + l16 * 4 + r;
            xp[2048 * r] = scl[prow] * acc[r] + bias;
        }
    }
    asm volatile("s_waitcnt vmcnt(0)" ::: "memory");
    __syncthreads();

    // ---- load dec B_hi into LDS ----
    for (int i = tid; i < 2048; i += 512) {
        const int kg = i >> 6, nc = i & 63;
        *(u16x8*)(sBe + i * 8) =
            *(const u16x8*)(BuH + ((size_t)kg * 2048 + w * 64 + nc) * 8);
    }
    __syncthreads();

    // =====================================================================
    // decoder: 64 steps, 1 sync each (per-dir, 16 slots); h parity dbuf
    // =====================================================================
    float cd = 0.f;
    const int durow = tid >> 4, dul = tid & 15;
    const float* xr = xw + (size_t)(g * 32 + durow) * 2048 + w * 64;
    for (int s = 0; s < 64; ++s) {
        if (s) { arrive_pub(pD, bw, (unsigned)s); wait_min(pD, (unsigned)s, 16); }
        const int par = s & 1;
        f32x4 acc = {0.f, 0.f, 0.f, 0.f};
        #pragma unroll
        for (int kw = 0; kw < 8; ++kw) {
            const int kg = kw * 4 + l16;           // 0..31
            const size_t ao = (size_t)(g * 32 + dlrow) * 256 + (size_t)kg * 8;
            const bf16x8 a_h = *(const bf16x8*)(hd[par][0] + ao);
            const bf16x8 a_l = *(const bf16x8*)(hd[par][1] + ao);
            const bf16x8 b_h = *(const bf16x8*)(sBe + (kg * 64 + dncl) * 8);
            const bf16x8 b_l = *(const bf16x8*)(BuL + ((size_t)kg * 2048 + dgcolp) * 8);
            acc = __builtin_amdgcn_mfma_f32_16x16x32_bf16(a_h, b_h, acc, 0, 0, 0);
            acc = __builtin_amdgcn_mfma_f32_16x16x32_bf16(a_h, b_l, acc, 0, 0, 0);
            acc = __builtin_amdgcn_mfma_f32_16x16x32_bf16(a_l, b_h, acc, 0, 0, 0);
        }
        #pragma unroll
        for (int r = 0; r < 4; ++r)
            zt[dncl * 33 + dmh * 16 + l16 * 4 + r] = acc[r];
        __syncthreads();
        {
            const float zi = zt[dul * 33 + durow]        + xr[dul];
            const float zf = zt[(16 + dul) * 33 + durow] + xr[16 + dul];
            const float zg = zt[(32 + dul) * 33 + durow] + xr[32 + dul];
            const float zo = zt[(48 + dul) * 33 + durow] + xr[48 + dul];
            const float cv = sigm(zf) * cd + sigm(zi) * tanhf(zg);
            cd = cv;
            const float hv = sigm(zo) * tanhf(cv);
            unsigned short hh, hl; split2(hv, hh, hl);
            const size_t hdix = (size_t)(g * 32 + durow) * 256 + bw * 16 + dul;
            hd[par ^ 1][0][hdix] = hh;
            hd[par ^ 1][1][hdix] = hl;
            const int tt = dir ? (63 - s) : s;
            hseqb[((size_t)(g * 32 + durow) * 64 + tt) * 512 + dir * 256 + bw * 16 + dul] = hh;
        }
        __syncthreads();
    }
    arrive_pub(pE, w, 1u); wait_min(pE, 1u, 32);   // hseq complete (both dirs)

    // =====================================================================
    // dense head: block w -> 64 bt rows of this group's 2048
    // =====================================================================
    {
        float* dkc = (float*)sBe;
        for (int i = tid; i < 8192; i += 512) dkc[i] = dK[i];
        __syncthreads();
        const int f = tid & 15;
        #pragma unroll
        for (int p = 0; p < 2; ++p) {
            const int bt = g * 2048 + w * 64 + (tid >> 4) + p * 32;
            const unsigned short* hs = hseqb + (size_t)bt * 512;
            float acc = dnB[f];
            #pragma unroll 4
            for (int k = 0; k < 512; k += 8) {
                const u16x8 hv = *(const u16x8*)(hs + k);
                #pragma unroll
                for (int j = 0; j < 8; ++j)
                    acc += bf2f(hv[j]) * dkc[(k + j) * 16 + f];
            }
            out[(size_t)bt * 16 + f] = acc;
        }
    }
}

// ---------------------------------------------------------------------------
extern "C" void kernel_launch(void* const* d_in, const int* in_sizes, int n_in,
                              void* d_out, int out_size, void* d_ws, size_t ws_size,
                              hipStream_t stream)
{
    const float* x    = (const float*)d_in[0];
    const float* encW = (const float*)d_in[1];
    const float* encU = (const float*)d_in[2];
    const float* encB = (const float*)d_in[3];
    const float* dfK  = (const float*)d_in[4];
    const float* dfU  = (const float*)d_in[5];
    const float* dfB  = (const float*)d_in[6];
    const float* dbK  = (const float*)d_in[7];
    const float* dbU  = (const float*)d_in[8];
    const float* dbB  = (const float*)d_in[9];
    const float* dK   = (const float*)d_in[10];
    const float* dnB  = (const float*)d_in[11];

    if (ws_size < WS_FLOATS * sizeof(float)) return;

    float* ws = (float*)d_ws;
    unsigned short* BencH = (unsigned short*)(ws + OFS_BENCH);
    unsigned short* BencL = (unsigned short*)(ws + OFS_BENCL);
    unsigned short* BdkH  = (unsigned short*)(ws + OFS_BDKH);
    unsigned short* BdkL  = (unsigned short*)(ws + OFS_BDKL);
    unsigned short* BduH  = (unsigned short*)(ws + OFS_BDUH);
    unsigned short* BduL  = (unsigned short*)(ws + OFS_BDUL);
    unsigned* bar = (unsigned*)(ws + OFS_BAR);

    pack_b<0><<<576, 256, 0, stream>>>(encW, encU, BencH, BencL, bar);
    pack_b<1><<<512, 256, 0, stream>>>(dfK, dbK, BdkH, BdkL, nullptr);
    pack_b<2><<<256, 256, 0, stream>>>(dfU, dbU, BduH, BduL, nullptr);

    lstm_all<<<256, 512, 0, stream>>>(x, encB, dfB, dbB, dK, dnB,
                                      (float*)d_out, ws);
}

// Round 14
// 2346.055 us; speedup vs baseline: 1.7869x; 1.1164x over previous
//
#include <hip/hip_runtime.h>
#include <math.h>

// ---------------------------------------------------------------------------
// LSTM encoder-decoder, 3-term bf16 MFMA (hi/lo split), persistent kernel.
// 8 XCD-local groups (bid&7), 32 blocks x 512 thr each, own 32 batch rows.
// Gate-grouped columns; TWO independent half-chains per block (r13-proven).
// r14: (1) FULL encoder B slice (hi+lo, 147KB) in LDS -> zero per-step B
// traffic (1 block/CU anyway; gfx950 LDS 160KB, HK precedent 128-160KB);
// (2) g-gate wave publishes stats1 partials DIRECTLY FROM MFMA REGISTERS
// (red16 over lane span) + early pA flag publish -> pA RTT overlaps zt-write/
// HB/sigmoid work; (3) HBs/step 4 -> 3. Sync primitive r10/r13-proven.
// ---------------------------------------------------------------------------

typedef __attribute__((ext_vector_type(8))) short bf16x8;
typedef __attribute__((ext_vector_type(8))) unsigned short u16x8;
typedef __attribute__((ext_vector_type(4))) float f32x4;

// ws layout (float offsets)
#define OFS_XW     0u          // 256*2048 f32
#define OFS_HEH    524288u     // enc h̃ hi PACKED [g][kg64][row32][8] (=65536 f)
#define OFS_HEL    589824u
#define OFS_HD     655360u     // dec h: [par2][dir2][hi/lo][256*256 bf16]
#define OFS_HSEQ   917504u     // 256*64*512 bf16 (=4194304 f)
#define OFS_BENCH  5111808u    // 72*2048*8 bf16 packed (gate-grouped cols)
#define OFS_BENCL  5701632u
#define OFS_BDKH   6291456u    // 64*2048*8
#define OFS_BDKL   6815744u
#define OFS_BDUH   7340032u    // 32*2048*8
#define OFS_BDUL   7602176u
#define OFS_PST    7864320u    // pst1: 8g*32row*32w*2f; pst2: +16384
#define OFS_BAR    7897088u    // 65536 u32, per g 8192: pC+0 pA0+1024 pA1+2048
                               //  pB0+3072 pB1+4096 pD+5120(2x512) pE+6144
#define WS_FLOATS  7962624u    // ~31.9 MB

__device__ __forceinline__ unsigned short bf_hi(float f) {
    union { float f; unsigned u; } v; v.f = f;
    unsigned r = v.u + 0x7fffu + ((v.u >> 16) & 1u);
    return (unsigned short)(r >> 16);
}
__device__ __forceinline__ float bf2f(unsigned short h) {
    union { unsigned u; float f; } v; v.u = ((unsigned)h) << 16;
    return v.f;
}
__device__ __forceinline__ void split2(float f, unsigned short& hi, unsigned short& lo) {
    hi = bf_hi(f);
    lo = bf_hi(f - bf2f(hi));
}
__device__ __forceinline__ float sigm(float x) { return 1.0f / (1.0f + __expf(-x)); }

// ---- cross-block spin (one wave; lanes gather slots; AGENT scope) ---------
__device__ __forceinline__ void gspin(unsigned* arr, unsigned tgt, int nslots) {
    const int lane = threadIdx.x & 63;
    const int idx = (lane < nslots) ? lane : 0;
    const long long t0 = clock64();
    for (;;) {
        unsigned v = __hip_atomic_load(arr + idx * 32, __ATOMIC_RELAXED,
                                       __HIP_MEMORY_SCOPE_AGENT);
        #pragma unroll
        for (int m = 32; m; m >>= 1) {
            const unsigned o = (unsigned)__shfl_xor((int)v, m, 64);
            v = (o < v) ? o : v;
        }
        if (v >= tgt) break;
        __builtin_amdgcn_s_sleep(1);
        if (clock64() - t0 > 4000000LL) break;   // deadlock guard only
    }
    asm volatile("buffer_inv sc0" ::: "memory");  // L1-only invalidate
}

// ---- sub-block LDS barrier (monotonic counter; 4 waves of a half) ---------
#define HB(cnt, tgt) do { \
    asm volatile("s_waitcnt vmcnt(0) lgkmcnt(0)" ::: "memory"); \
    if ((threadIdx.x & 63) == 0) atomicAdd((cnt), 1u); \
    const long long _hb0 = clock64(); \
    while (__hip_atomic_load((cnt), __ATOMIC_RELAXED, \
                             __HIP_MEMORY_SCOPE_WORKGROUP) < (tgt)) { \
        __builtin_amdgcn_s_sleep(0); \
        if (clock64() - _hb0 > 8000000LL) break; } \
    asm volatile("" ::: "memory"); } while (0)

#define LDS_SPIN(ptr, tgt) do { \
    const long long _ls0 = clock64(); \
    while (__hip_atomic_load((ptr), __ATOMIC_RELAXED, \
                             __HIP_MEMORY_SCOPE_WORKGROUP) < (tgt)) { \
        __builtin_amdgcn_s_sleep(0); \
        if (clock64() - _ls0 > 8000000LL) break; } \
    asm volatile("" ::: "memory"); } while (0)

// ---- full-block sync helpers (decoder; r12-proven) ------------------------
__device__ __forceinline__ void arrive_pub(unsigned* arr, int slot, unsigned val) {
    asm volatile("s_waitcnt vmcnt(0) lgkmcnt(0)" ::: "memory");
    __syncthreads();
    if (threadIdx.x == 0)
        __hip_atomic_store(arr + slot * 32, val, __ATOMIC_RELAXED,
                           __HIP_MEMORY_SCOPE_AGENT);
}
__device__ __forceinline__ void wait_min(unsigned* arr, unsigned tgt, int nslots) {
    if (threadIdx.x < 64) gspin(arr, tgt, nslots);
    __syncthreads();
}

// 16-lane-span reductions
__device__ __forceinline__ float red16max(float v) {
    #pragma unroll
    for (int m = 8; m; m >>= 1) v = fmaxf(v, __shfl_xor(v, m, 64));
    return v;
}
__device__ __forceinline__ float red16sum(float v) {
    #pragma unroll
    for (int m = 8; m; m >>= 1) v += __shfl_xor(v, m, 64);
    return v;
}

// ---------------------------------------------------------------------------
// weight pack (r9-proven). MODE 0 zeroes the 65536 barrier words.
// ---------------------------------------------------------------------------
template <int MODE>
__global__ __launch_bounds__(256) void pack_b(
    const float* __restrict__ S0, const float* __restrict__ S1,
    unsigned short* __restrict__ H, unsigned short* __restrict__ L,
    unsigned* __restrict__ bar)
{
    const int idx = blockIdx.x * 256 + threadIdx.x;
    if (MODE == 0 && idx < 65536) bar[idx] = 0u;
    const int n = idx & 2047, kg = idx >> 11;
    int sc;
    const float* Sd;
    if (MODE == 0) {
        sc = ((n >> 4) & 3) * 512 + (n >> 6) * 16 + (n & 15);
        Sd = nullptr;
    } else {
        const int dir = n >> 10, bw = (n >> 6) & 15;
        sc = ((n >> 4) & 3) * 256 + bw * 16 + (n & 15);
        Sd = dir ? S1 : S0;
    }
    u16x8 h8, l8;
    #pragma unroll
    for (int j = 0; j < 8; ++j) {
        const int k = kg * 8 + j;
        float v;
        if (MODE == 0) v = (k < 64) ? S0[(size_t)k * 2048 + sc] : S1[(size_t)(k - 64) * 2048 + sc];
        else           v = Sd[(size_t)k * 1024 + sc];
        unsigned short hh, ll; split2(v, hh, ll);
        h8[j] = hh; l8[j] = ll;
    }
    *(u16x8*)(H + (size_t)idx * 8) = h8;
    *(u16x8*)(L + (size_t)idx * 8) = l8;
}

// ===========================================================================
// Persistent kernel. 256 blocks x 512 thr (8 waves), LDS ~156KB -> 1/CU
// (256 blocks on 256 CUs). g=bid&7 (XCD), w=bid>>3 (0..31).
// Enc waves: half=wid>>2, gate=wid&3.
// ===========================================================================
__global__ __launch_bounds__(512, 1) void lstm_all(
    const float* __restrict__ x, const float* __restrict__ encB,
    const float* __restrict__ dfB, const float* __restrict__ dbB,
    const float* __restrict__ dK, const float* __restrict__ dnB,
    float* __restrict__ out, float* __restrict__ ws)
{
    const int bid = blockIdx.x, tid = threadIdx.x;
    const int g = bid & 7, w = bid >> 3;
    const int lane = tid & 63, wid = tid >> 6;
    const int half = wid >> 2, gate = wid & 3;    // enc wave roles
    const int l16 = lane >> 4, lr = lane & 15;
    const int lrow = half * 16 + lr;              // enc A row (group-local)
    const int grow = g * 32 + lrow;
    const int ncl  = gate * 16 + lr;              // block-local col
    const int tidh = tid & 255;
    const int urh = tidh >> 4, ul = tidh & 15;    // update ids within half
    const int urow = half * 16 + urh;             // group-local row

    float* xw = ws + OFS_XW;
    unsigned short* hEHu = (unsigned short*)(ws + OFS_HEH);   // packed h̃ hi
    unsigned short* hELu = (unsigned short*)(ws + OFS_HEL);
    unsigned short* hseqb = (unsigned short*)(ws + OFS_HSEQ);
    const unsigned short* BeH = (const unsigned short*)(ws + OFS_BENCH);
    const unsigned short* BeL = (const unsigned short*)(ws + OFS_BENCL);
    const unsigned short* BkH = (const unsigned short*)(ws + OFS_BDKH);
    const unsigned short* BkL = (const unsigned short*)(ws + OFS_BDKL);
    const unsigned short* BuH = (const unsigned short*)(ws + OFS_BDUH);
    const unsigned short* BuL = (const unsigned short*)(ws + OFS_BDUL);
    float* pst1 = ws + OFS_PST + (unsigned)g * 2048u;
    float* pst2 = ws + OFS_PST + 16384u + (unsigned)g * 2048u;
    unsigned* barg = (unsigned*)(ws + OFS_BAR) + g * 8192;
    unsigned* pC = barg;
    unsigned* pAh[2] = {barg + 1024, barg + 2048};
    unsigned* pBh[2] = {barg + 3072, barg + 4096};
    unsigned* pE = barg + 6144;

    // LDS: full enc B slice hi+lo (72kg x 64col x 8 = 73728B each) + aux
    __shared__ __align__(16) unsigned short sBeH[36864];
    __shared__ __align__(16) unsigned short sBeL[36864];
    __shared__ __align__(16) float zt[2112];             // [64 cols][33]
    __shared__ float scl[32];
    __shared__ unsigned harr[2], hrel[2];

    const int dir = w >> 4, bw = w & 15;
    unsigned* pD = barg + 5120 + dir * 512;
    unsigned short* hd[2][2];
    #pragma unroll
    for (int p = 0; p < 2; ++p)
        #pragma unroll
        for (int hl_ = 0; hl_ < 2; ++hl_)
            hd[p][hl_] = (unsigned short*)(ws + OFS_HD +
                          (unsigned)((p * 2 + dir) * 2 + hl_) * 32768u);

    if (tid < 2) { harr[tid] = 0u; hrel[tid] = 0u; }

    // ---- init: zero own h̃ slice (packed) + dec h; pst2 := (0,1) ----
    {
        const int urow32 = tid >> 4, ul32 = tid & 15;     // full-block ids
        const int u = w * 16 + ul32;
        const size_t he = ((size_t)(g * 64 + (u >> 3)) * 32 + urow32) * 8 + (u & 7);
        hEHu[he] = 0; hELu[he] = 0;
        const size_t hdix = (size_t)(g * 32 + urow32) * 256 + bw * 16 + ul32;
        #pragma unroll
        for (int p = 0; p < 2; ++p) { hd[p][0][hdix] = 0; hd[p][1][hdix] = 0; }
        if (ul32 == 0) *(float2*)(pst2 + (urow32 * 32 + w) * 2) = float2{0.f, 1.f};
    }
    for (int i = tid; i < 4608; i += 512) {       // full enc B (hi+lo) -> LDS
        const int kg = i >> 6, nc = i & 63;
        const size_t src = ((size_t)kg * 2048 + w * 64 + nc) * 8;
        *(u16x8*)(sBeH + i * 8) = *(const u16x8*)(BeH + src);
        *(u16x8*)(sBeL + i * 8) = *(const u16x8*)(BeL + src);
    }
    arrive_pub(pC, w, 1u);                        // init published (syncthreads)

    const float encBias = encB[gate * 512 + w * 16 + lr];
    float c = 0.f;

    // =====================================================================
    // encoder: 256 steps; two independent half-chains; NO __syncthreads
    // =====================================================================
    for (int t = 0; t < 256; ++t) {
        // ---- x-part GEMM (no h̃ dependency; B from LDS) ----
        f32x4 ax = {0.f, 0.f, 0.f, 0.f};
        #pragma unroll
        for (int kw = 0; kw < 2; ++kw) {
            const int kg = kw * 4 + l16;
            const float* xp = x + (size_t)grow * 16384 + t * 64 + kg * 8;
            const float4 x0 = *(const float4*)xp;
            const float4 x1 = *(const float4*)(xp + 4);
            const float xs[8] = {x0.x, x0.y, x0.z, x0.w, x1.x, x1.y, x1.z, x1.w};
            bf16x8 a_h, a_l;
            #pragma unroll
            for (int j = 0; j < 8; ++j) {
                unsigned short hh, ll; split2(xs[j], hh, ll);
                a_h[j] = (short)hh; a_l[j] = (short)ll;
            }
            const bf16x8 b_h = *(const bf16x8*)(sBeH + (kg * 64 + ncl) * 8);
            const bf16x8 b_l = *(const bf16x8*)(sBeL + (kg * 64 + ncl) * 8);
            ax = __builtin_amdgcn_mfma_f32_16x16x32_bf16(a_h, b_h, ax, 0, 0, 0);
            ax = __builtin_amdgcn_mfma_f32_16x16x32_bf16(a_h, b_l, ax, 0, 0, 0);
            ax = __builtin_amdgcn_mfma_f32_16x16x32_bf16(a_l, b_h, ax, 0, 0, 0);
        }
        // ---- half-chain wait: h̃(t-1)+pst2(t-1) from all blocks ----
        if (gate == 0) {
            if (t == 0) gspin(pC, 1u, 32);
            else        gspin(pBh[half], (unsigned)t, 32);
            if (lane == 0) atomicAdd(&hrel[half], 1u);
        }
        LDS_SPIN(&hrel[half], (unsigned)(2 * t + 1));

        // ---- per-row scale from pst2 (own half's rows) ----
        {
            const float2 pa = *(const float2*)(pst2 + (urow * 32 + ul) * 2);
            const float2 pb = *(const float2*)(pst2 + (urow * 32 + ul + 16) * 2);
            const float ml = fmaxf(pa.x, pb.x);
            const float sl = pa.y * __expf(pa.x - ml) + pb.y * __expf(pb.x - ml);
            const float M2 = red16max(ml);
            const float S2 = red16sum(sl * __expf(ml - M2));
            if (ul == 0) scl[urow] = __expf(-M2) / S2;
        }
        HB(&harr[half], 4u * (3 * t + 1));

        // ---- h̃-part GEMM (packed A from L2; B entirely from LDS) ----
        f32x4 ah = {0.f, 0.f, 0.f, 0.f};
        #pragma unroll
        for (int kw = 2; kw < 18; ++kw) {
            const int kg = kw * 4 + l16;          // 8..71
            const size_t ao = ((size_t)(g * 64 + (kg - 8)) * 32 + lrow) * 8;
            const bf16x8 a_h = *(const bf16x8*)(hEHu + ao);
            const bf16x8 a_l = *(const bf16x8*)(hELu + ao);
            const bf16x8 b_h = *(const bf16x8*)(sBeH + (kg * 64 + ncl) * 8);
            const bf16x8 b_l = *(const bf16x8*)(sBeL + (kg * 64 + ncl) * 8);
            ah = __builtin_amdgcn_mfma_f32_16x16x32_bf16(a_h, b_h, ah, 0, 0, 0);
            ah = __builtin_amdgcn_mfma_f32_16x16x32_bf16(a_h, b_l, ah, 0, 0, 0);
            ah = __builtin_amdgcn_mfma_f32_16x16x32_bf16(a_l, b_h, ah, 0, 0, 0);
        }
        // final z in registers
        float v[4];
        #pragma unroll
        for (int r = 0; r < 4; ++r) {
            const int row = half * 16 + l16 * 4 + r;
            v[r] = scl[row] * ah[r] + ax[r] + encBias;
        }
        // ---- g-gate wave: stats1 partials FROM REGISTERS + early pA pub ----
        if (gate == 2) {
            #pragma unroll
            for (int r = 0; r < 4; ++r) {
                const float mw = red16max(v[r]);
                const float sw = red16sum(__expf(v[r] - mw));
                if (lr == 0) {
                    const int row = half * 16 + l16 * 4 + r;
                    *(float2*)(pst1 + (row * 32 + w) * 2) = float2{mw, sw};
                }
            }
            asm volatile("s_waitcnt vmcnt(0)" ::: "memory");
            if (lane == 0)
                __hip_atomic_store(pAh[half] + w * 32, (unsigned)(t + 1),
                                   __ATOMIC_RELAXED, __HIP_MEMORY_SCOPE_AGENT);
        }
        #pragma unroll
        for (int r = 0; r < 4; ++r)
            zt[ncl * 33 + half * 16 + l16 * 4 + r] = v[r];
        HB(&harr[half], 4u * (3 * t + 2));        // zt ready

        // ---- sigmoids (pA detection overlaps this) ----
        const float zg = zt[(32 + ul) * 33 + urow];
        const float si = sigm(zt[ul * 33 + urow]);
        const float sf = sigm(zt[(16 + ul) * 33 + urow]);
        const float so = sigm(zt[(48 + ul) * 33 + urow]);

        if (gate == 0) {
            gspin(pAh[half], (unsigned)(t + 1), 32);
            if (lane == 0) atomicAdd(&hrel[half], 1u);
        }
        LDS_SPIN(&hrel[half], (unsigned)(2 * t + 2));

        // ---- combine stats1; c update; publish h̃ (packed) + stats2 ----
        {
            const float2 pa = *(const float2*)(pst1 + (urow * 32 + ul) * 2);
            const float2 pb = *(const float2*)(pst1 + (urow * 32 + ul + 16) * 2);
            const float ml = fmaxf(pa.x, pb.x);
            const float sl = pa.y * __expf(pa.x - ml) + pb.y * __expf(pb.x - ml);
            const float M = red16max(ml);
            const float S = red16sum(sl * __expf(ml - M));
            c = sf * c + si * (__expf(zg - M) / S);
        }
        {
            const float ht = so * __expf(c);
            unsigned short hh, hl; split2(ht, hh, hl);
            const int u = w * 16 + ul;
            const size_t he = ((size_t)(g * 64 + (u >> 3)) * 32 + urow) * 8 + (u & 7);
            hEHu[he] = hh;
            hELu[he] = hl;
            const float m2 = red16max(c);
            const float s2 = red16sum(__expf(c - m2));
            if (ul == 0) *(float2*)(pst2 + (urow * 32 + w) * 2) = float2{m2, s2};
        }
        HB(&harr[half], 4u * (3 * t + 3));        // h̃+pst2 drained
        if (gate == 0 && lane == 0)
            __hip_atomic_store(pBh[half] + w * 32, (unsigned)(t + 1),
                               __ATOMIC_RELAXED, __HIP_MEMORY_SCOPE_AGENT);
    }

    // ---- rejoin halves; wait all blocks' final h̃ ----
    __syncthreads();
    wait_min(pBh[0], 256u, 32);
    wait_min(pBh[1], 256u, 32);

    // =====================================================================
    // decoder input projection: xw = scale_row*(h̃ @ Bdk) + bias
    // =====================================================================
    {
        const int urow32 = tid >> 4, ul32 = tid & 15;
        const float2 pa = *(const float2*)(pst2 + (urow32 * 32 + ul32) * 2);
        const float2 pb = *(const float2*)(pst2 + (urow32 * 32 + ul32 + 16) * 2);
        const float ml = fmaxf(pa.x, pb.x);
        const float sl = pa.y * __expf(pa.x - ml) + pb.y * __expf(pb.x - ml);
        const float M2 = red16max(ml);
        const float S2 = red16sum(sl * __expf(ml - M2));
        if (ul32 == 0) scl[urow32] = __expf(-M2) / S2;
    }
    __syncthreads();
    const int dmh = wid & 1, dnh = wid >> 1;       // dec wave roles
    const int dlrow = dmh * 16 + lr;
    const int dncl = dnh * 16 + lr;
    const int dgcolp = w * 64 + dncl;
    {
        const float bias = (dir ? dbB : dfB)[dnh * 256 + bw * 16 + lr];
        f32x4 acc = {0.f, 0.f, 0.f, 0.f};
        #pragma unroll
        for (int kw = 0; kw < 16; ++kw) {
            const int kg = kw * 4 + l16;           // 0..63
            const size_t ao = ((size_t)(g * 64 + kg) * 32 + dlrow) * 8;
            const bf16x8 a_h = *(const bf16x8*)(hEHu + ao);
            const bf16x8 a_l = *(const bf16x8*)(hELu + ao);
            const size_t bo = ((size_t)kg * 2048 + dgcolp) * 8;
            const bf16x8 b_h = *(const bf16x8*)(BkH + bo);
            const bf16x8 b_l = *(const bf16x8*)(BkL + bo);
            acc = __builtin_amdgcn_mfma_f32_16x16x32_bf16(a_h, b_h, acc, 0, 0, 0);
            acc = __builtin_amdgcn_mfma_f32_16x16x32_bf16(a_h, b_l, acc, 0, 0, 0);
            acc = __builtin_amdgcn_mfma_f32_16x16x32_bf16(a_l, b_h, acc, 0, 0, 0);
        }
        float* xp = xw + (size_t)(g * 32 + dmh * 16 + l16 * 4) * 2048 + dgcolp;
        #pragma unroll
        for (int r = 0; r < 4; ++r) {
            const int prow = dmh * 16 + l16 * 4 + r;
            xp[2048 * r] = scl[prow] * acc[r] + bias;
        }
    }
    asm volatile("s_waitcnt vmcnt(0)" ::: "memory");
    __syncthreads();

    // ---- load dec B (hi+lo) into LDS ----
    for (int i = tid; i < 2048; i += 512) {
        const int kg = i >> 6, nc = i & 63;
        const size_t src = ((size_t)kg * 2048 + w * 64 + nc) * 8;
        *(u16x8*)(sBeH + i * 8) = *(const u16x8*)(BuH + src);
        *(u16x8*)(sBeL + i * 8) = *(const u16x8*)(BuL + src);
    }
    __syncthreads();

    // =====================================================================
    // decoder: 64 steps, 1 sync each (per-dir, 16 slots); h parity dbuf
    // =====================================================================
    float cd = 0.f;
    const int durow = tid >> 4, dul = tid & 15;
    const float* xr = xw + (size_t)(g * 32 + durow) * 2048 + w * 64;
    for (int s = 0; s < 64; ++s) {
        if (s) { arrive_pub(pD, bw, (unsigned)s); wait_min(pD, (unsigned)s, 16); }
        const int par = s & 1;
        f32x4 acc = {0.f, 0.f, 0.f, 0.f};
        #pragma unroll
        for (int kw = 0; kw < 8; ++kw) {
            const int kg = kw * 4 + l16;           // 0..31
            const size_t ao = (size_t)(g * 32 + dlrow) * 256 + (size_t)kg * 8;
            const bf16x8 a_h = *(const bf16x8*)(hd[par][0] + ao);
            const bf16x8 a_l = *(const bf16x8*)(hd[par][1] + ao);
            const bf16x8 b_h = *(const bf16x8*)(sBeH + (kg * 64 + dncl) * 8);
            const bf16x8 b_l = *(const bf16x8*)(sBeL + (kg * 64 + dncl) * 8);
            acc = __builtin_amdgcn_mfma_f32_16x16x32_bf16(a_h, b_h, acc, 0, 0, 0);
            acc = __builtin_amdgcn_mfma_f32_16x16x32_bf16(a_h, b_l, acc, 0, 0, 0);
            acc = __builtin_amdgcn_mfma_f32_16x16x32_bf16(a_l, b_h, acc, 0, 0, 0);
        }
        #pragma unroll
        for (int r = 0; r < 4; ++r)
            zt[dncl * 33 + dmh * 16 + l16 * 4 + r] = acc[r];
        __syncthreads();
        {
            const float zi = zt[dul * 33 + durow]        + xr[dul];
            const float zf = zt[(16 + dul) * 33 + durow] + xr[16 + dul];
            const float zg = zt[(32 + dul) * 33 + durow] + xr[32 + dul];
            const float zo = zt[(48 + dul) * 33 + durow] + xr[48 + dul];
            const float cv = sigm(zf) * cd + sigm(zi) * tanhf(zg);
            cd = cv;
            const float hv = sigm(zo) * tanhf(cv);
            unsigned short hh, hl; split2(hv, hh, hl);
            const size_t hdix = (size_t)(g * 32 + durow) * 256 + bw * 16 + dul;
            hd[par ^ 1][0][hdix] = hh;
            hd[par ^ 1][1][hdix] = hl;
            const int tt = dir ? (63 - s) : s;
            hseqb[((size_t)(g * 32 + durow) * 64 + tt) * 512 + dir * 256 + bw * 16 + dul] = hh;
        }
        __syncthreads();
    }
    arrive_pub(pE, w, 1u); wait_min(pE, 1u, 32);   // hseq complete (both dirs)

    // =====================================================================
    // dense head: block w -> 64 bt rows of this group's 2048
    // =====================================================================
    {
        float* dkc = (float*)sBeH;
        for (int i = tid; i < 8192; i += 512) dkc[i] = dK[i];
        __syncthreads();
        const int f = tid & 15;
        #pragma unroll
        for (int p = 0; p < 2; ++p) {
            const int bt = g * 2048 + w * 64 + (tid >> 4) + p * 32;
            const unsigned short* hs = hseqb + (size_t)bt * 512;
            float acc = dnB[f];
            #pragma unroll 4
            for (int k = 0; k < 512; k += 8) {
                const u16x8 hv = *(const u16x8*)(hs + k);
                #pragma unroll
                for (int j = 0; j < 8; ++j)
                    acc += bf2f(hv[j]) * dkc[(k + j) * 16 + f];
            }
            out[(size_t)bt * 16 + f] = acc;
        }
    }
}

// ---------------------------------------------------------------------------
extern "C" void kernel_launch(void* const* d_in, const int* in_sizes, int n_in,
                              void* d_out, int out_size, void* d_ws, size_t ws_size,
                              hipStream_t stream)
{
    const float* x    = (const float*)d_in[0];
    const float* encW = (const float*)d_in[1];
    const float* encU = (const float*)d_in[2];
    const float* encB = (const float*)d_in[3];
    const float* dfK  = (const float*)d_in[4];
    const float* dfU  = (const float*)d_in[5];
    const float* dfB  = (const float*)d_in[6];
    const float* dbK  = (const float*)d_in[7];
    const float* dbU  = (const float*)d_in[8];
    const float* dbB  = (const float*)d_in[9];
    const float* dK   = (const float*)d_in[10];
    const float* dnB  = (const float*)d_in[11];

    if (ws_size < WS_FLOATS * sizeof(float)) return;

    float* ws = (float*)d_ws;
    unsigned short* BencH = (unsigned short*)(ws + OFS_BENCH);
    unsigned short* BencL = (unsigned short*)(ws + OFS_BENCL);
    unsigned short* BdkH  = (unsigned short*)(ws + OFS_BDKH);
    unsigned short* BdkL  = (unsigned short*)(ws + OFS_BDKL);
    unsigned short* BduH  = (unsigned short*)(ws + OFS_BDUH);
    unsigned short* BduL  = (unsigned short*)(ws + OFS_BDUL);
    unsigned* bar = (unsigned*)(ws + OFS_BAR);

    pack_b<0><<<576, 256, 0, stream>>>(encW, encU, BencH, BencL, bar);
    pack_b<1><<<512, 256, 0, stream>>>(dfK, dbK, BdkH, BdkL, nullptr);
    pack_b<2><<<256, 256, 0, stream>>>(dfU, dbU, BduH, BduL, nullptr);

    lstm_all<<<256, 512, 0, stream>>>(x, encB, dfB, dbB, dK, dnB,
                                      (float*)d_out, ws);
}